// Round 14
// baseline (1450.597 us; speedup 1.0000x reference)
//
#include <hip/hip_runtime.h>
#include <cfloat>
#include <climits>

// SparseEncoder forward, MI355X (gfx950). rows=4096, d=2048, m=16384, k=64.
// R14: GEMM 256x128 tile, BK=32, THREE LDS buffers (144KB) -> depth-2 prefetch
// with counted vmcnt (never drains to 0 in main loop; T3+T4). 2 barriers/chunk.
// Rest byte-identical to R13/R11.

typedef __attribute__((ext_vector_type(8))) short short8;
typedef __attribute__((ext_vector_type(4))) float f32x4;

#define NC      96
#define KFIN    64
#define TAU     1e-3f
#define AUXC    0.03125f
#define MCONC   16384
#define DDIM    2048
#define CAP     768     // topk candidate buffer capacity (= 3*256 exactly)

__device__ __forceinline__ ushort f2bf(float f) {
  unsigned u = __float_as_uint(f);
  u += 0x7fff + ((u >> 16) & 1);   // RTN-even
  return (ushort)(u >> 16);
}
__device__ __forceinline__ float bf2f(ushort h) {
  return __uint_as_float(((unsigned)h) << 16);
}

// ---------------- init / dead-concept bookkeeping ----------------
__global__ void k_init(float* dead_sum, int* n_dead, int* wl_count) {
  *dead_sum = 0.f;
  *n_dead = 0;
  *wl_count = 0;
}

__global__ void k_count_dead(const int* __restrict__ steps, const int* __restrict__ dw,
                             int m, int* __restrict__ n_dead) {
  int i = blockIdx.x * blockDim.x + threadIdx.x;
  if (i < m && steps[i] >= *dw) atomicAdd(n_dead, 1);
}

__global__ void k_final(const float* __restrict__ ds, const int* __restrict__ nd,
                        float* __restrict__ outp, float BT) {
  int n = *nd;
  float denom = fmaxf((float)n * BT, 1.0f);
  outp[0] = (n > 0) ? -((*ds) / denom) * AUXC : 0.0f;
}

// ---------------- fused prep: A/B hi-lo staging + W_emb transpose->bf16 ----------------
__global__ __launch_bounds__(256)
void k_prep(const float* __restrict__ srcA, ushort* __restrict__ dstA, int totA,
            const float* __restrict__ srcB, ushort* __restrict__ dstB, int totB,
            int K,
            const float* __restrict__ Wemb, ushort* __restrict__ WembT,
            int d, int m, int nstage) {
  __shared__ float tile[32][33];
  const int b = blockIdx.x;
  if (b < nstage) {
    int idx = b * 256 + threadIdx.x;
    const float* src;
    ushort* dst;
    int t;
    if (idx < totA) { src = srcA; dst = dstA; t = idx; }
    else if (idx < totA + totB) { src = srcB; dst = dstB; t = idx - totA; }
    else return;
    int nch = K >> 5;
    int row = t / nch, c = t - row * nch;
    const float* s = src + (size_t)row * K + c * 32;
    float f[32];
#pragma unroll
    for (int q = 0; q < 8; ++q) *(float4*)&f[q * 4] = *(const float4*)(s + q * 4);
    ushort hi[32];
    float lof[32];
#pragma unroll
    for (int e = 0; e < 32; ++e) {
      hi[e] = f2bf(f[e]);
      lof[e] = f[e] - bf2f(hi[e]);
    }
    ushort* dd = dst + (size_t)row * ((size_t)K * 2) + c * 64;
#pragma unroll
    for (int q = 0; q < 4; ++q) {
      short8 o;
#pragma unroll
      for (int e = 0; e < 8; ++e) o[e] = (short)hi[q * 8 + e];
      *(short8*)(dd + q * 8) = o;
    }
#pragma unroll
    for (int q = 0; q < 4; ++q) {
      short8 o;
#pragma unroll
      for (int e = 0; e < 8; ++e) o[e] = (short)f2bf(lof[q * 8 + e]);
      *(short8*)(dd + 32 + q * 8) = o;
    }
    return;
  }
  // transpose segment: W_emb [d,m] fp32 -> WembT [m,d] bf16
  const int tb = b - nstage;
  const int nmb = m >> 5;
  const int mb = (tb % nmb) * 32, db = (tb / nmb) * 32;
  const int tx = threadIdx.x & 31, ty = threadIdx.x >> 5;
#pragma unroll
  for (int i = 0; i < 32; i += 8)
    tile[ty + i][tx] = Wemb[(size_t)(db + ty + i) * m + mb + tx];
  __syncthreads();
#pragma unroll
  for (int i = 0; i < 32; i += 8)
    WembT[(size_t)(mb + ty + i) * d + db + tx] = f2bf(tile[tx][ty + i]);
}

// ---------------- bf16x3 MFMA GEMM, 256x128 tile, 3-buffer counted-vmcnt ----------------
__device__ __forceinline__ void gload16(const void* g, void* l) {
  __builtin_amdgcn_global_load_lds((const __attribute__((address_space(1))) void*)g,
                                   (__attribute__((address_space(3))) void*)l, 16, 0, 0);
}

// 1-D grid, XCD-bijective swizzle (m204), bn fastest (A L2-resident per XCD).
// 512 threads = 8 waves (4x2 wm x wn), per-wave C = 64x64 (acc 4x4 f32x4).
// LDS: 3 x (A 32KB + B 16KB) = 144KB -> 1 block/CU. Depth-2 prefetch:
// while computing chunk j, chunks j+1 and j+2 are in flight; main-loop wait
// is s_waitcnt vmcnt(12) (6 loads/chunk/wave) -- never 0 until the tail.
__global__ __launch_bounds__(512, 2)
void k_gemm3(const ushort* __restrict__ Ast, const ushort* __restrict__ Bst,
             const float* __restrict__ bias, float* __restrict__ C,
             int row0, int K, int m, int nbm) {
  __shared__ ushort As[3][256 * 64];   // 32KB each
  __shared__ ushort Bs[3][128 * 64];   // 16KB each
  const int tid = threadIdx.x;
  const int lane = tid & 63, w = tid >> 6;     // w in 0..7
  const int wm = w >> 1, wn = w & 1;           // 4 x 2 wave grid

  const int nbn = m >> 7;                      // 128-wide bn panels
  const int nwg = nbm * nbn;
  const int q = nwg >> 3, r = nwg & 7;
  const int x = blockIdx.x & 7, i0 = blockIdx.x >> 3;
  const int wg = (x < r) ? x * (q + 1) + i0 : r * (q + 1) + (x - r) * q + i0;
  const int bm = wg / nbn, bn = wg % nbn;      // bn fastest: A-panel L2 reuse

  const size_t K2 = (size_t)K * 2;
  const int nch = K >> 5;

  const int gr = lane >> 3;
  const int swz = (((lane & 7) ^ gr) << 3);
  const size_t arow0 = (size_t)(row0 + bm * 256);
  const size_t brow0 = (size_t)(bn * 128);

  f32x4 acc[4][4];
#pragma unroll
  for (int i = 0; i < 4; ++i)
#pragma unroll
    for (int j = 0; j < 4; ++j) acc[i][j] = (f32x4)(0.f);

  const int kg = lane >> 4;
  const int j7 = lane & 7;
  const int sh = ((kg ^ j7) << 3);
  const int rbase = (lane & 15) * 64;

  // 6 gload16 per thread per chunk: 4 for A (rows 0..255), 2 for B (rows 0..127)
  auto STAGE = [&](int buf, int c) {
#pragma unroll
    for (int t = 0; t < 4; ++t) {
      int i = w * 4 + t;                // 0..31
      int rr = i * 8 + gr;              // 0..255
      gload16(Ast + (arow0 + rr) * K2 + (size_t)c * 64 + swz, (void*)(As[buf] + i * 512));
    }
#pragma unroll
    for (int t = 0; t < 2; ++t) {
      int i = w * 2 + t;                // 0..15
      int rr = i * 8 + gr;              // 0..127
      gload16(Bst + (brow0 + rr) * K2 + (size_t)c * 64 + swz, (void*)(Bs[buf] + i * 512));
    }
  };

  STAGE(0, 0);
  if (nch > 1) STAGE(1, 1);

  for (int j = 0; j < nch; ++j) {
    const int cur = j % 3;
    // prefetch chunk j+2 into buf (j+2)%3 (== the buffer read at iter j-1)
    if (j + 2 < nch) {
      STAGE((j + 2) % 3, j + 2);
      asm volatile("s_waitcnt vmcnt(12)" ::: "memory");  // chunk-j loads retired
    } else if (j + 1 < nch) {
      asm volatile("s_waitcnt vmcnt(6)" ::: "memory");
    } else {
      asm volatile("s_waitcnt vmcnt(0)" ::: "memory");
    }
    asm volatile("s_barrier" ::: "memory");              // all waves see chunk j

    short8 ah[4], al[4], bh[4], bl[4];
#pragma unroll
    for (int f = 0; f < 4; ++f) {
      const ushort* pa = As[cur] + (wm * 64 + f * 16) * 64 + rbase;
      ah[f] = *(const short8*)(pa + sh);
      al[f] = *(const short8*)(pa + (sh ^ 32));
      const ushort* pb = Bs[cur] + (wn * 64 + f * 16) * 64 + rbase;
      bh[f] = *(const short8*)(pb + sh);
      bl[f] = *(const short8*)(pb + (sh ^ 32));
    }
    __builtin_amdgcn_s_setprio(1);
#pragma unroll
    for (int fm = 0; fm < 4; ++fm)
#pragma unroll
      for (int fn = 0; fn < 4; ++fn) {
        acc[fm][fn] = __builtin_amdgcn_mfma_f32_16x16x32_bf16(ah[fm], bh[fn], acc[fm][fn], 0, 0, 0);
        acc[fm][fn] = __builtin_amdgcn_mfma_f32_16x16x32_bf16(ah[fm], bl[fn], acc[fm][fn], 0, 0, 0);
        acc[fm][fn] = __builtin_amdgcn_mfma_f32_16x16x32_bf16(al[fm], bh[fn], acc[fm][fn], 0, 0, 0);
      }
    __builtin_amdgcn_s_setprio(0);
    asm volatile("s_barrier" ::: "memory");              // reads done before overwrite
  }

  // epilogue: C/D layout col=lane&15, row=(lane>>4)*4+reg; nt stores spare L3
  const int orow = bm * 256 + wm * 64;
  const int ocol = bn * 128 + wn * 64;
#pragma unroll
  for (int fn = 0; fn < 4; ++fn) {
    float bb = bias[ocol + fn * 16 + (lane & 15)];
#pragma unroll
    for (int fm = 0; fm < 4; ++fm) {
      int rb = orow + fm * 16 + (lane >> 4) * 4;
#pragma unroll
      for (int rr = 0; rr < 4; ++rr)
        __builtin_nontemporal_store(acc[fm][fn][rr] + bb,
            &C[(size_t)(rb + rr) * m + ocol + fn * 16 + (lane & 15)]);
    }
  }
}

// ---------------- top-NC + fused flag/worklist + unflagged final write ----------------
__global__ __launch_bounds__(256)
void k_topk(const float* __restrict__ preact, int row0,
            const int* __restrict__ steps, const int* __restrict__ dw,
            const int* __restrict__ topk_d,
            float* __restrict__ cvals, int* __restrict__ cidx,
            float* __restrict__ dead_sum,
            int* __restrict__ rowflag, int* __restrict__ wl, int* __restrict__ wl_count,
            float* __restrict__ tvals, int* __restrict__ tidx) {
  __shared__ float dred[4];
  __shared__ float wmx[4], wmn[4];
  __shared__ float sm1[4], sm2[4];
  __shared__ int scnt;
  __shared__ int pos;
  __shared__ float cval_s[CAP];
  __shared__ int cidx_s[CAP];
  __shared__ float vk1_s, vk_s;
  __shared__ int flag_s;
  const int tid = threadIdx.x;
  const int lane = tid & 63;
  const int grow = row0 + blockIdx.x;
  const float* pr = preact + (size_t)blockIdx.x * MCONC;

  int kt = *topk_d;
  if (kt > KFIN) kt = KFIN;
  if (kt < 1) kt = 1;

  float v[64];
#pragma unroll
  for (int c = 0; c < 16; ++c) {
    const f32x4* p4 = (const f32x4*)(pr + (size_t)c * 1024 + tid * 4);
    f32x4 t4 = __builtin_nontemporal_load(p4);
    v[c * 4 + 0] = t4[0]; v[c * 4 + 1] = t4[1];
    v[c * 4 + 2] = t4[2]; v[c * 4 + 3] = t4[3];
  }

  // dead-concept masked sum (all-zero mask at init)
  int dwv = *dw;
  float ds = 0.f;
#pragma unroll
  for (int c = 0; c < 16; ++c) {
    int4 st = *(const int4*)(steps + c * 1024 + tid * 4);
    if (st.x >= dwv) ds += v[c * 4 + 0];
    if (st.y >= dwv) ds += v[c * 4 + 1];
    if (st.z >= dwv) ds += v[c * 4 + 2];
    if (st.w >= dwv) ds += v[c * 4 + 3];
  }
  for (int off = 32; off; off >>= 1) ds += __shfl_down(ds, off);
  if (lane == 0) dred[tid >> 6] = ds;

  // row max/min + mean/std moments (for the threshold probe)
  float mx = -FLT_MAX, mn = FLT_MAX, s1 = 0.f, s2 = 0.f;
#pragma unroll
  for (int i = 0; i < 64; ++i) {
    mx = fmaxf(mx, v[i]); mn = fminf(mn, v[i]);
    s1 += v[i]; s2 = fmaf(v[i], v[i], s2);
  }
  for (int off = 32; off; off >>= 1) {
    mx = fmaxf(mx, __shfl_xor(mx, off));
    mn = fminf(mn, __shfl_xor(mn, off));
    s1 += __shfl_xor(s1, off);
    s2 += __shfl_xor(s2, off);
  }
  if (lane == 0) { wmx[tid >> 6] = mx; wmn[tid >> 6] = mn; sm1[tid >> 6] = s1; sm2[tid >> 6] = s2; }
  __syncthreads();
  if (tid == 0) {
    float t = dred[0] + dred[1] + dred[2] + dred[3];
    if (t != 0.f) atomicAdd(dead_sum, t);
  }
  float row_mx = fmaxf(fmaxf(wmx[0], wmx[1]), fmaxf(wmx[2], wmx[3]));
  float row_mn = fminf(fminf(wmn[0], wmn[1]), fminf(wmn[2], wmn[3]));
  float T1 = sm1[0] + sm1[1] + sm1[2] + sm1[3];
  float T2 = sm2[0] + sm2[1] + sm2[2] + sm2[3];
  float mu = T1 * (1.f / 16384.f);
  float var = fmaxf(T2 * (1.f / 16384.f) - mu * mu, 0.f);
  float mid = mu + 2.0f * sqrtf(var);

  // threshold search: smart probe first, exact binary-search fallback
  float lo = row_mn - 1.0f, hi = row_mx;
  float t = lo;
  bool found = false;
  for (int it = 0; it < 23 && !found; ++it) {
    __syncthreads();
    if (tid == 0) scnt = 0;
    __syncthreads();
    int cl = 0;
#pragma unroll
    for (int i = 0; i < 64; ++i) cl += (v[i] > mid);
    for (int off = 32; off; off >>= 1) cl += __shfl_xor(cl, off);
    if (lane == 0) atomicAdd(&scnt, cl);
    __syncthreads();
    int cnt = scnt;
    if (cnt >= NC && cnt <= CAP) { t = mid; found = true; }
    else if (cnt < NC) hi = mid;
    else lo = mid;
    mid = 0.5f * (lo + hi);
  }
  if (!found) t = lo;  // count(>lo) >= NC invariant

  // compact candidates to LDS
  __syncthreads();
  if (tid == 0) pos = 0;
  __syncthreads();
#pragma unroll
  for (int i = 0; i < 64; ++i) {
    if (v[i] > t) {
      int p = atomicAdd(&pos, 1);
      if (p < CAP) {
        cval_s[p] = v[i];
        cidx_s[p] = ((i >> 2) << 10) | (tid << 2) | (i & 3);
      }
    }
  }
  __syncthreads();
  int Cn = pos < CAP ? pos : CAP;

  // parallel rank (strict total order: value desc, index asc).
  int rnk[3];
  float mvv[3];
  int mii[3];
#pragma unroll
  for (int jj = 0; jj < 3; ++jj) {
    int j = tid + jj * 256;
    rnk[jj] = INT_MAX;
    if (j < Cn) {
      float my = cval_s[j];
      int myidx = cidx_s[j];
      int rank = 0;
      for (int c = 0; c < Cn; ++c) {
        float o = cval_s[c];
        rank += (o > my) || (o == my && cidx_s[c] < myidx);
      }
      rnk[jj] = rank; mvv[jj] = my; mii[jj] = myidx;
      if (rank < NC) {
        cvals[(size_t)grow * NC + rank] = my;
        cidx[(size_t)grow * NC + rank] = myidx;
      }
      if (rank == kt - 1) vk1_s = my;
      if (rank == kt)     vk_s  = my;
    }
  }
  __syncthreads();
  if (tid == 0) {
    int f = (vk1_s - vk_s < TAU) ? 1 : 0;
    rowflag[grow] = f;
    flag_s = f;
    if (f) { int p = atomicAdd(wl_count, 1); wl[p] = grow; }
  }
  __syncthreads();
  if (!flag_s) {
#pragma unroll
    for (int jj = 0; jj < 3; ++jj) {
      if (rnk[jj] < kt) {
        tvals[(size_t)grow * KFIN + rnk[jj]] = mvv[jj];
        tidx[(size_t)grow * KFIN + rnk[jj]] = mii[jj];
      }
    }
  }
}

// ---------------- parallel fp64 candidate dots (worklist, grid-stride) ----------------
__global__ __launch_bounds__(256)
void k_dots(const int* __restrict__ wl, const int* __restrict__ wl_count,
            const int* __restrict__ cidx, const float* __restrict__ act,
            const float* __restrict__ Wenc, const float* __restrict__ bias,
            double* __restrict__ dv, int d) {
  __shared__ float arow[DDIM];
  const int total = (*wl_count) * 8;
  const int lane = threadIdx.x & 63, w = threadIdx.x >> 6;
  for (int b = blockIdx.x; b < total; b += gridDim.x) {
    const int row = wl[b >> 3], part = b & 7;
    __syncthreads();   // guard arow reuse across stride iterations
    for (int i = threadIdx.x; i < d; i += 256) arow[i] = act[(size_t)row * d + i];
    __syncthreads();
#pragma unroll
    for (int cc = 0; cc < 3; ++cc) {
      int c = part * 12 + w * 3 + cc;
      int ci = cidx[(size_t)row * NC + c];
      const float* wrow = Wenc + (size_t)ci * d;
      double s = 0.0;
      for (int i = lane; i < d; i += 64)
        s += (double)arow[i] * (double)wrow[i];
      for (int off = 32; off; off >>= 1) s += __shfl_down(s, off);
      if (lane == 0) dv[(size_t)row * NC + c] = s + (double)bias[ci];
    }
  }
}

// ---------------- final selection for FLAGGED rows only ----------------
__global__ __launch_bounds__(128)
void k_select(const float* __restrict__ cvals, const int* __restrict__ cidx,
              const int* __restrict__ rowflag, const double* __restrict__ dv,
              const int* __restrict__ topk_d,
              float* __restrict__ tvals, int* __restrict__ tidx) {
  const int row = blockIdx.x, tid = threadIdx.x;
  if (!rowflag[row]) return;   // unflagged rows already written by k_topk
  int kt = *topk_d;
  if (kt > KFIN) kt = KFIN;
  if (kt < 1) kt = 1;
  __shared__ double sdv[NC];
  if (tid < NC) sdv[tid] = dv[(size_t)row * NC + tid];
  __syncthreads();
  if (tid < NC) {
    double my = sdv[tid];
    int rank = 0;
#pragma unroll 8
    for (int c = 0; c < NC; ++c) {
      double v = sdv[c];
      rank += (v > my) || (v == my && c < tid);
    }
    if (rank < kt) {
      tvals[(size_t)row * KFIN + rank] = cvals[(size_t)row * NC + tid];
      tidx[(size_t)row * KFIN + rank] = cidx[(size_t)row * NC + tid];
    }
  }
}

// ---------------- sparse decode (bf16 transposed weights) ----------------
__global__ __launch_bounds__(256)
void k_decode_t(const float* __restrict__ tvals, const int* __restrict__ tidx,
                const int* __restrict__ topk_d, const ushort* __restrict__ Wt,
                float* __restrict__ out, int d) {
  __shared__ float sv[KFIN];
  __shared__ int si[KFIN];
  const int row = blockIdx.x, tid = threadIdx.x;
  int kt = *topk_d;
  if (kt > KFIN) kt = KFIN;
  if (tid < kt) {
    sv[tid] = tvals[(size_t)row * KFIN + tid];
    si[tid] = tidx[(size_t)row * KFIN + tid];
  }
  __syncthreads();
  for (int base = tid * 8; base < d; base += 2048) {
    float a0 = 0, a1 = 0, a2 = 0, a3 = 0, a4 = 0, a5 = 0, a6 = 0, a7 = 0;
#pragma unroll 4
    for (int j = 0; j < kt; ++j) {
      float vv = sv[j];
      short8 wv = *(const short8*)(Wt + (size_t)si[j] * d + base);
      a0 = fmaf(vv, bf2f((ushort)wv[0]), a0);
      a1 = fmaf(vv, bf2f((ushort)wv[1]), a1);
      a2 = fmaf(vv, bf2f((ushort)wv[2]), a2);
      a3 = fmaf(vv, bf2f((ushort)wv[3]), a3);
      a4 = fmaf(vv, bf2f((ushort)wv[4]), a4);
      a5 = fmaf(vv, bf2f((ushort)wv[5]), a5);
      a6 = fmaf(vv, bf2f((ushort)wv[6]), a6);
      a7 = fmaf(vv, bf2f((ushort)wv[7]), a7);
    }
    float* o = out + (size_t)row * d + base;
    *(float4*)o = make_float4(a0, a1, a2, a3);
    *(float4*)(o + 4) = make_float4(a4, a5, a6, a7);
  }
}

// fallback: gather directly from W_emb [d,m] fp32
__global__ __launch_bounds__(256)
void k_decode_g(const float* __restrict__ tvals, const int* __restrict__ tidx,
                const int* __restrict__ topk_d, const float* __restrict__ Wemb,
                float* __restrict__ out, int d, int m) {
  __shared__ float sv[KFIN];
  __shared__ int si[KFIN];
  const int row = blockIdx.x, tid = threadIdx.x;
  int kt = *topk_d;
  if (kt > KFIN) kt = KFIN;
  if (tid < kt) {
    sv[tid] = tvals[(size_t)row * KFIN + tid];
    si[tid] = tidx[(size_t)row * KFIN + tid];
  }
  __syncthreads();
  for (int base = tid * 8; base < d; base += 2048) {
    float acc[8] = {0, 0, 0, 0, 0, 0, 0, 0};
    for (int j = 0; j < kt; ++j) {
      float vv = sv[j];
      int ix = si[j];
#pragma unroll
      for (int e = 0; e < 8; ++e)
        acc[e] = fmaf(vv, Wemb[(size_t)(base + e) * m + ix], acc[e]);
    }
    float* o = out + (size_t)row * d + base;
    *(float4*)o = *(float4*)&acc[0];
    *(float4*)(o + 4) = *(float4*)&acc[4];
  }
}

// ---------------- host ----------------
extern "C" void kernel_launch(void* const* d_in, const int* in_sizes, int n_in,
                              void* d_out, int out_size, void* d_ws, size_t ws_size,
                              hipStream_t stream) {
  const float* act   = (const float*)d_in[0];
  const float* Wenc  = (const float*)d_in[1];
  const float* benc  = (const float*)d_in[2];
  const float* Wemb  = (const float*)d_in[3];
  const int*   steps = (const int*)d_in[4];
  const int*   topk  = (const int*)d_in[5];
  const int*   dwin  = (const int*)d_in[6];
  const int m = in_sizes[2];          // 16384
  const int d = in_sizes[1] / m;      // 2048
  const int rows = in_sizes[0] / d;   // 4096
  float* out = (float*)d_out;

  char* ws = (char*)d_ws;
  float* dead_sum = (float*)ws;
  int*   n_dead   = (int*)(ws + 8);
  int*   wl_count = (int*)(ws + 16);
  size_t off = 256;
  float* cvals = (float*)(ws + off); off += (size_t)rows * NC * 4;
  int*   cidx  = (int*)(ws + off);   off += (size_t)rows * NC * 4;
  float* tvals = (float*)(ws + off); off += (size_t)rows * KFIN * 4;
  int*   tidx  = (int*)(ws + off);   off += (size_t)rows * KFIN * 4;
  int*   rowflag = (int*)(ws + off); off += (size_t)rows * 4;
  int*   wl      = (int*)(ws + off); off += (size_t)rows * 4;
  double* dv     = (double*)(ws + off); off += (size_t)rows * NC * 8;
  ushort* Ast  = (ushort*)(ws + off); off += (size_t)rows * d * 4;  // hi+lo bf16
  ushort* Bst  = (ushort*)(ws + off); off += (size_t)m * d * 4;

  const size_t wembT_bytes = (size_t)m * d * sizeof(ushort);  // bf16
  const size_t row_bytes = (size_t)m * sizeof(float);
  size_t avail = (ws_size > off) ? ws_size - off : 0;

  ushort* WembT = nullptr;
  if (avail >= wembT_bytes + 256 * row_bytes) {
    WembT = (ushort*)(ws + off);
    off += wembT_bytes;
    avail -= wembT_bytes;
  }
  int chunk = (int)(avail / row_bytes);
  if (chunk > rows) chunk = rows;
  chunk &= ~255;                      // 256-row GEMM tiles
  if (chunk < 256) chunk = 256;
  float* preact = (float*)(ws + off);

  k_init<<<1, 1, 0, stream>>>(dead_sum, n_dead, wl_count);
  k_count_dead<<<(m + 255) / 256, 256, 0, stream>>>(steps, dwin, m, n_dead);

  int totA = rows * (d >> 5);
  int totB = m * (d >> 5);
  int nstage = (totA + totB + 255) / 256;
  int ntrans = WembT ? (m / 32) * (d / 32) : 0;
  k_prep<<<nstage + ntrans, 256, 0, stream>>>(act, Ast, totA, Wenc, Bst, totB, d,
                                              Wemb, WembT, d, m, nstage);

  for (int r0 = 0; r0 < rows; r0 += chunk) {
    int cr = rows - r0;
    if (cr > chunk) cr = chunk;
    int nbm = cr / 256;
    int nwg = nbm * (m / 128);
    k_gemm3<<<nwg, 512, 0, stream>>>(Ast, Bst, benc, preact, r0, d, m, nbm);
    k_topk<<<cr, 256, 0, stream>>>(preact, r0, steps, dwin, topk,
                                   cvals, cidx, dead_sum,
                                   rowflag, wl, wl_count, tvals, tidx);
  }

  k_dots<<<rows, 256, 0, stream>>>(wl, wl_count, cidx, act, Wenc, benc, dv, d);
  k_select<<<rows, 128, 0, stream>>>(cvals, cidx, rowflag, dv, topk, tvals, tidx);

  if (WembT) {
    k_decode_t<<<rows, 256, 0, stream>>>(tvals, tidx, topk, WembT, out, d);
  } else {
    k_decode_g<<<rows, 256, 0, stream>>>(tvals, tidx, topk, Wemb, out, d, m);
  }

  k_final<<<1, 1, 0, stream>>>(dead_sum, n_dead, out + (size_t)rows * d, (float)rows);
}

// Round 15
// 1150.581 us; speedup vs baseline: 1.2608x; 1.2608x over previous
//
#include <hip/hip_runtime.h>
#include <cfloat>
#include <climits>

// SparseEncoder forward, MI355X (gfx950). rows=4096, d=2048, m=16384, k=64.
// R15 = R13 restored (best: 1151us). 256x256 GEMM, 4-phase double-buffered
// schedule, launch_bounds(512,2). R14's 3-buffer counted-vmcnt regressed
// (asm barrier w/ memory clobber forced vmcnt(0) drains per chunk).

typedef __attribute__((ext_vector_type(8))) short short8;
typedef __attribute__((ext_vector_type(4))) float f32x4;

#define NC      96
#define KFIN    64
#define TAU     1e-3f
#define AUXC    0.03125f
#define MCONC   16384
#define DDIM    2048
#define CAP     768     // topk candidate buffer capacity (= 3*256 exactly)

__device__ __forceinline__ ushort f2bf(float f) {
  unsigned u = __float_as_uint(f);
  u += 0x7fff + ((u >> 16) & 1);   // RTN-even
  return (ushort)(u >> 16);
}
__device__ __forceinline__ float bf2f(ushort h) {
  return __uint_as_float(((unsigned)h) << 16);
}

// ---------------- init / dead-concept bookkeeping ----------------
__global__ void k_init(float* dead_sum, int* n_dead, int* wl_count) {
  *dead_sum = 0.f;
  *n_dead = 0;
  *wl_count = 0;
}

__global__ void k_count_dead(const int* __restrict__ steps, const int* __restrict__ dw,
                             int m, int* __restrict__ n_dead) {
  int i = blockIdx.x * blockDim.x + threadIdx.x;
  if (i < m && steps[i] >= *dw) atomicAdd(n_dead, 1);
}

__global__ void k_final(const float* __restrict__ ds, const int* __restrict__ nd,
                        float* __restrict__ outp, float BT) {
  int n = *nd;
  float denom = fmaxf((float)n * BT, 1.0f);
  outp[0] = (n > 0) ? -((*ds) / denom) * AUXC : 0.0f;
}

// ---------------- fused prep: A/B hi-lo staging + W_emb transpose->bf16 ----------------
__global__ __launch_bounds__(256)
void k_prep(const float* __restrict__ srcA, ushort* __restrict__ dstA, int totA,
            const float* __restrict__ srcB, ushort* __restrict__ dstB, int totB,
            int K,
            const float* __restrict__ Wemb, ushort* __restrict__ WembT,
            int d, int m, int nstage) {
  __shared__ float tile[32][33];
  const int b = blockIdx.x;
  if (b < nstage) {
    int idx = b * 256 + threadIdx.x;
    const float* src;
    ushort* dst;
    int t;
    if (idx < totA) { src = srcA; dst = dstA; t = idx; }
    else if (idx < totA + totB) { src = srcB; dst = dstB; t = idx - totA; }
    else return;
    int nch = K >> 5;
    int row = t / nch, c = t - row * nch;
    const float* s = src + (size_t)row * K + c * 32;
    float f[32];
#pragma unroll
    for (int q = 0; q < 8; ++q) *(float4*)&f[q * 4] = *(const float4*)(s + q * 4);
    ushort hi[32];
    float lof[32];
#pragma unroll
    for (int e = 0; e < 32; ++e) {
      hi[e] = f2bf(f[e]);
      lof[e] = f[e] - bf2f(hi[e]);
    }
    ushort* dd = dst + (size_t)row * ((size_t)K * 2) + c * 64;
#pragma unroll
    for (int q = 0; q < 4; ++q) {
      short8 o;
#pragma unroll
      for (int e = 0; e < 8; ++e) o[e] = (short)hi[q * 8 + e];
      *(short8*)(dd + q * 8) = o;
    }
#pragma unroll
    for (int q = 0; q < 4; ++q) {
      short8 o;
#pragma unroll
      for (int e = 0; e < 8; ++e) o[e] = (short)f2bf(lof[q * 8 + e]);
      *(short8*)(dd + 32 + q * 8) = o;
    }
    return;
  }
  // transpose segment: W_emb [d,m] fp32 -> WembT [m,d] bf16
  const int tb = b - nstage;
  const int nmb = m >> 5;
  const int mb = (tb % nmb) * 32, db = (tb / nmb) * 32;
  const int tx = threadIdx.x & 31, ty = threadIdx.x >> 5;
#pragma unroll
  for (int i = 0; i < 32; i += 8)
    tile[ty + i][tx] = Wemb[(size_t)(db + ty + i) * m + mb + tx];
  __syncthreads();
#pragma unroll
  for (int i = 0; i < 32; i += 8)
    WembT[(size_t)(mb + ty + i) * d + db + tx] = f2bf(tile[tx][ty + i]);
}

// ---------------- bf16x3 MFMA GEMM, 256x256 tile, 8 waves, 4-phase pipeline ----------------
__device__ __forceinline__ void gload16(const void* g, void* l) {
  __builtin_amdgcn_global_load_lds((const __attribute__((address_space(1))) void*)g,
                                   (__attribute__((address_space(3))) void*)l, 16, 0, 0);
}

// 1-D grid, XCD-bijective swizzle (m204), bn fastest (A L2-resident per XCD).
// 512 threads = 8 waves (2x4). LDS: 2 x (A 32KB + B 32KB) = 128KB -> 1 block/CU.
__global__ __launch_bounds__(512, 2)
void k_gemm3(const ushort* __restrict__ Ast, const ushort* __restrict__ Bst,
             const float* __restrict__ bias, float* __restrict__ C,
             int row0, int K, int m, int nbm) {
  __shared__ ushort As[2][256 * 64];
  __shared__ ushort Bs[2][256 * 64];
  const int tid = threadIdx.x;
  const int lane = tid & 63, w = tid >> 6;     // w in 0..7
  const int wm = w >> 2, wn = w & 3;           // 2 x 4 wave grid

  const int nbn = m >> 8;
  const int nwg = nbm * nbn;
  const int q = nwg >> 3, r = nwg & 7;
  const int x = blockIdx.x & 7, i0 = blockIdx.x >> 3;
  const int wg = (x < r) ? x * (q + 1) + i0 : r * (q + 1) + (x - r) * q + i0;
  const int bm = wg / nbn, bn = wg % nbn;      // bn fastest: A-panel L2 reuse

  const size_t K2 = (size_t)K * 2;
  const int nch = K >> 5;

  const int gr = lane >> 3;
  const int swz = (((lane & 7) ^ gr) << 3);
  const size_t arow0 = (size_t)(row0 + bm * 256);
  const size_t brow0 = (size_t)(bn * 256);

  f32x4 acc[8][4];
#pragma unroll
  for (int i = 0; i < 8; ++i)
#pragma unroll
    for (int j = 0; j < 4; ++j) acc[i][j] = (f32x4)(0.f);

  const int kg = lane >> 4;
  const int j7 = lane & 7;
  const int sh = ((kg ^ j7) << 3);
  const int rbase = (lane & 15) * 64;

  auto STAGE_A = [&](int buf, int c) {
#pragma unroll
    for (int t = 0; t < 4; ++t) {
      int i = w * 4 + t;
      int rr = i * 8 + gr;
      gload16(Ast + (arow0 + rr) * K2 + (size_t)c * 64 + swz, (void*)(As[buf] + i * 512));
    }
  };
  auto STAGE_B = [&](int buf, int c) {
#pragma unroll
    for (int t = 0; t < 4; ++t) {
      int i = w * 4 + t;
      int rr = i * 8 + gr;
      gload16(Bst + (brow0 + rr) * K2 + (size_t)c * 64 + swz, (void*)(Bs[buf] + i * 512));
    }
  };

  STAGE_A(0, 0);
  STAGE_B(0, 0);
  __syncthreads();                 // prologue drain: chunk 0 landed

  int cur = 0;
  for (int j = 0; j < nch; ++j) {
    short8 bh[4], bl[4];
#pragma unroll
    for (int ph = 0; ph < 4; ++ph) {
      if (ph == 0) {
#pragma unroll
        for (int fn = 0; fn < 4; ++fn) {
          const ushort* pb = Bs[cur] + (wn * 64 + fn * 16) * 64 + rbase;
          bh[fn] = *(const short8*)(pb + sh);
          bl[fn] = *(const short8*)(pb + (sh ^ 32));
        }
      }
      const ushort* pa0 = As[cur] + (wm * 128 + (2 * ph + 0) * 16) * 64 + rbase;
      const ushort* pa1 = As[cur] + (wm * 128 + (2 * ph + 1) * 16) * 64 + rbase;
      short8 ah0 = *(const short8*)(pa0 + sh);
      short8 al0 = *(const short8*)(pa0 + (sh ^ 32));
      short8 ah1 = *(const short8*)(pa1 + sh);
      short8 al1 = *(const short8*)(pa1 + (sh ^ 32));
      // stage next chunk: A-half at ph0, B-half at ph1.
      if (j + 1 < nch) {
        if (ph == 0) STAGE_A(cur ^ 1, j + 1);
        else if (ph == 1) STAGE_B(cur ^ 1, j + 1);
      }
      __builtin_amdgcn_s_barrier();
      __builtin_amdgcn_s_setprio(1);
#pragma unroll
      for (int fn = 0; fn < 4; ++fn) {
        acc[2 * ph + 0][fn] = __builtin_amdgcn_mfma_f32_16x16x32_bf16(ah0, bh[fn], acc[2 * ph + 0][fn], 0, 0, 0);
        acc[2 * ph + 0][fn] = __builtin_amdgcn_mfma_f32_16x16x32_bf16(ah0, bl[fn], acc[2 * ph + 0][fn], 0, 0, 0);
        acc[2 * ph + 0][fn] = __builtin_amdgcn_mfma_f32_16x16x32_bf16(al0, bh[fn], acc[2 * ph + 0][fn], 0, 0, 0);
        acc[2 * ph + 1][fn] = __builtin_amdgcn_mfma_f32_16x16x32_bf16(ah1, bh[fn], acc[2 * ph + 1][fn], 0, 0, 0);
        acc[2 * ph + 1][fn] = __builtin_amdgcn_mfma_f32_16x16x32_bf16(ah1, bl[fn], acc[2 * ph + 1][fn], 0, 0, 0);
        acc[2 * ph + 1][fn] = __builtin_amdgcn_mfma_f32_16x16x32_bf16(al1, bh[fn], acc[2 * ph + 1][fn], 0, 0, 0);
      }
      __builtin_amdgcn_s_setprio(0);
      __builtin_amdgcn_s_barrier();
    }
    __syncthreads();               // chunk-end: waits loads issued >=2 phases ago
    cur ^= 1;
  }

  // epilogue: C/D layout col=lane&15, row=(lane>>4)*4+reg
  const int orow = bm * 256 + wm * 128;
  const int ocol = bn * 256 + wn * 64;
#pragma unroll
  for (int fn = 0; fn < 4; ++fn) {
    float bb = bias[ocol + fn * 16 + (lane & 15)];
#pragma unroll
    for (int fm = 0; fm < 8; ++fm) {
      int rb = orow + fm * 16 + (lane >> 4) * 4;
#pragma unroll
      for (int rr = 0; rr < 4; ++rr)
        __builtin_nontemporal_store(acc[fm][fn][rr] + bb,
            &C[(size_t)(rb + rr) * m + ocol + fn * 16 + (lane & 15)]);
    }
  }
}

// ---------------- top-NC + fused flag/worklist + unflagged final write ----------------
__global__ __launch_bounds__(256)
void k_topk(const float* __restrict__ preact, int row0,
            const int* __restrict__ steps, const int* __restrict__ dw,
            const int* __restrict__ topk_d,
            float* __restrict__ cvals, int* __restrict__ cidx,
            float* __restrict__ dead_sum,
            int* __restrict__ rowflag, int* __restrict__ wl, int* __restrict__ wl_count,
            float* __restrict__ tvals, int* __restrict__ tidx) {
  __shared__ float dred[4];
  __shared__ float wmx[4], wmn[4];
  __shared__ float sm1[4], sm2[4];
  __shared__ int scnt;
  __shared__ int pos;
  __shared__ float cval_s[CAP];
  __shared__ int cidx_s[CAP];
  __shared__ float vk1_s, vk_s;
  __shared__ int flag_s;
  const int tid = threadIdx.x;
  const int lane = tid & 63;
  const int grow = row0 + blockIdx.x;
  const float* pr = preact + (size_t)blockIdx.x * MCONC;

  int kt = *topk_d;
  if (kt > KFIN) kt = KFIN;
  if (kt < 1) kt = 1;

  float v[64];
#pragma unroll
  for (int c = 0; c < 16; ++c) {
    const f32x4* p4 = (const f32x4*)(pr + (size_t)c * 1024 + tid * 4);
    f32x4 t4 = __builtin_nontemporal_load(p4);
    v[c * 4 + 0] = t4[0]; v[c * 4 + 1] = t4[1];
    v[c * 4 + 2] = t4[2]; v[c * 4 + 3] = t4[3];
  }

  // dead-concept masked sum (all-zero mask at init)
  int dwv = *dw;
  float ds = 0.f;
#pragma unroll
  for (int c = 0; c < 16; ++c) {
    int4 st = *(const int4*)(steps + c * 1024 + tid * 4);
    if (st.x >= dwv) ds += v[c * 4 + 0];
    if (st.y >= dwv) ds += v[c * 4 + 1];
    if (st.z >= dwv) ds += v[c * 4 + 2];
    if (st.w >= dwv) ds += v[c * 4 + 3];
  }
  for (int off = 32; off; off >>= 1) ds += __shfl_down(ds, off);
  if (lane == 0) dred[tid >> 6] = ds;

  // row max/min + mean/std moments (for the threshold probe)
  float mx = -FLT_MAX, mn = FLT_MAX, s1 = 0.f, s2 = 0.f;
#pragma unroll
  for (int i = 0; i < 64; ++i) {
    mx = fmaxf(mx, v[i]); mn = fminf(mn, v[i]);
    s1 += v[i]; s2 = fmaf(v[i], v[i], s2);
  }
  for (int off = 32; off; off >>= 1) {
    mx = fmaxf(mx, __shfl_xor(mx, off));
    mn = fminf(mn, __shfl_xor(mn, off));
    s1 += __shfl_xor(s1, off);
    s2 += __shfl_xor(s2, off);
  }
  if (lane == 0) { wmx[tid >> 6] = mx; wmn[tid >> 6] = mn; sm1[tid >> 6] = s1; sm2[tid >> 6] = s2; }
  __syncthreads();
  if (tid == 0) {
    float t = dred[0] + dred[1] + dred[2] + dred[3];
    if (t != 0.f) atomicAdd(dead_sum, t);
  }
  float row_mx = fmaxf(fmaxf(wmx[0], wmx[1]), fmaxf(wmx[2], wmx[3]));
  float row_mn = fminf(fminf(wmn[0], wmn[1]), fminf(wmn[2], wmn[3]));
  float T1 = sm1[0] + sm1[1] + sm1[2] + sm1[3];
  float T2 = sm2[0] + sm2[1] + sm2[2] + sm2[3];
  float mu = T1 * (1.f / 16384.f);
  float var = fmaxf(T2 * (1.f / 16384.f) - mu * mu, 0.f);
  float mid = mu + 2.0f * sqrtf(var);

  // threshold search: smart probe first, exact binary-search fallback
  float lo = row_mn - 1.0f, hi = row_mx;
  float t = lo;
  bool found = false;
  for (int it = 0; it < 23 && !found; ++it) {
    __syncthreads();
    if (tid == 0) scnt = 0;
    __syncthreads();
    int cl = 0;
#pragma unroll
    for (int i = 0; i < 64; ++i) cl += (v[i] > mid);
    for (int off = 32; off; off >>= 1) cl += __shfl_xor(cl, off);
    if (lane == 0) atomicAdd(&scnt, cl);
    __syncthreads();
    int cnt = scnt;
    if (cnt >= NC && cnt <= CAP) { t = mid; found = true; }
    else if (cnt < NC) hi = mid;
    else lo = mid;
    mid = 0.5f * (lo + hi);
  }
  if (!found) t = lo;  // count(>lo) >= NC invariant

  // compact candidates to LDS
  __syncthreads();
  if (tid == 0) pos = 0;
  __syncthreads();
#pragma unroll
  for (int i = 0; i < 64; ++i) {
    if (v[i] > t) {
      int p = atomicAdd(&pos, 1);
      if (p < CAP) {
        cval_s[p] = v[i];
        cidx_s[p] = ((i >> 2) << 10) | (tid << 2) | (i & 3);
      }
    }
  }
  __syncthreads();
  int Cn = pos < CAP ? pos : CAP;

  // parallel rank (strict total order: value desc, index asc).
  int rnk[3];
  float mvv[3];
  int mii[3];
#pragma unroll
  for (int jj = 0; jj < 3; ++jj) {
    int j = tid + jj * 256;
    rnk[jj] = INT_MAX;
    if (j < Cn) {
      float my = cval_s[j];
      int myidx = cidx_s[j];
      int rank = 0;
      for (int c = 0; c < Cn; ++c) {
        float o = cval_s[c];
        rank += (o > my) || (o == my && cidx_s[c] < myidx);
      }
      rnk[jj] = rank; mvv[jj] = my; mii[jj] = myidx;
      if (rank < NC) {
        cvals[(size_t)grow * NC + rank] = my;
        cidx[(size_t)grow * NC + rank] = myidx;
      }
      if (rank == kt - 1) vk1_s = my;
      if (rank == kt)     vk_s  = my;
    }
  }
  __syncthreads();
  if (tid == 0) {
    int f = (vk1_s - vk_s < TAU) ? 1 : 0;
    rowflag[grow] = f;
    flag_s = f;
    if (f) { int p = atomicAdd(wl_count, 1); wl[p] = grow; }
  }
  __syncthreads();
  if (!flag_s) {
#pragma unroll
    for (int jj = 0; jj < 3; ++jj) {
      if (rnk[jj] < kt) {
        tvals[(size_t)grow * KFIN + rnk[jj]] = mvv[jj];
        tidx[(size_t)grow * KFIN + rnk[jj]] = mii[jj];
      }
    }
  }
}

// ---------------- parallel fp64 candidate dots (worklist, grid-stride) ----------------
__global__ __launch_bounds__(256)
void k_dots(const int* __restrict__ wl, const int* __restrict__ wl_count,
            const int* __restrict__ cidx, const float* __restrict__ act,
            const float* __restrict__ Wenc, const float* __restrict__ bias,
            double* __restrict__ dv, int d) {
  __shared__ float arow[DDIM];
  const int total = (*wl_count) * 8;
  const int lane = threadIdx.x & 63, w = threadIdx.x >> 6;
  for (int b = blockIdx.x; b < total; b += gridDim.x) {
    const int row = wl[b >> 3], part = b & 7;
    __syncthreads();   // guard arow reuse across stride iterations
    for (int i = threadIdx.x; i < d; i += 256) arow[i] = act[(size_t)row * d + i];
    __syncthreads();
#pragma unroll
    for (int cc = 0; cc < 3; ++cc) {
      int c = part * 12 + w * 3 + cc;
      int ci = cidx[(size_t)row * NC + c];
      const float* wrow = Wenc + (size_t)ci * d;
      double s = 0.0;
      for (int i = lane; i < d; i += 64)
        s += (double)arow[i] * (double)wrow[i];
      for (int off = 32; off; off >>= 1) s += __shfl_down(s, off);
      if (lane == 0) dv[(size_t)row * NC + c] = s + (double)bias[ci];
    }
  }
}

// ---------------- final selection for FLAGGED rows only ----------------
__global__ __launch_bounds__(128)
void k_select(const float* __restrict__ cvals, const int* __restrict__ cidx,
              const int* __restrict__ rowflag, const double* __restrict__ dv,
              const int* __restrict__ topk_d,
              float* __restrict__ tvals, int* __restrict__ tidx) {
  const int row = blockIdx.x, tid = threadIdx.x;
  if (!rowflag[row]) return;   // unflagged rows already written by k_topk
  int kt = *topk_d;
  if (kt > KFIN) kt = KFIN;
  if (kt < 1) kt = 1;
  __shared__ double sdv[NC];
  if (tid < NC) sdv[tid] = dv[(size_t)row * NC + tid];
  __syncthreads();
  if (tid < NC) {
    double my = sdv[tid];
    int rank = 0;
#pragma unroll 8
    for (int c = 0; c < NC; ++c) {
      double v = sdv[c];
      rank += (v > my) || (v == my && c < tid);
    }
    if (rank < kt) {
      tvals[(size_t)row * KFIN + rank] = cvals[(size_t)row * NC + tid];
      tidx[(size_t)row * KFIN + rank] = cidx[(size_t)row * NC + tid];
    }
  }
}

// ---------------- sparse decode (bf16 transposed weights) ----------------
__global__ __launch_bounds__(256)
void k_decode_t(const float* __restrict__ tvals, const int* __restrict__ tidx,
                const int* __restrict__ topk_d, const ushort* __restrict__ Wt,
                float* __restrict__ out, int d) {
  __shared__ float sv[KFIN];
  __shared__ int si[KFIN];
  const int row = blockIdx.x, tid = threadIdx.x;
  int kt = *topk_d;
  if (kt > KFIN) kt = KFIN;
  if (tid < kt) {
    sv[tid] = tvals[(size_t)row * KFIN + tid];
    si[tid] = tidx[(size_t)row * KFIN + tid];
  }
  __syncthreads();
  for (int base = tid * 8; base < d; base += 2048) {
    float a0 = 0, a1 = 0, a2 = 0, a3 = 0, a4 = 0, a5 = 0, a6 = 0, a7 = 0;
#pragma unroll 4
    for (int j = 0; j < kt; ++j) {
      float vv = sv[j];
      short8 wv = *(const short8*)(Wt + (size_t)si[j] * d + base);
      a0 = fmaf(vv, bf2f((ushort)wv[0]), a0);
      a1 = fmaf(vv, bf2f((ushort)wv[1]), a1);
      a2 = fmaf(vv, bf2f((ushort)wv[2]), a2);
      a3 = fmaf(vv, bf2f((ushort)wv[3]), a3);
      a4 = fmaf(vv, bf2f((ushort)wv[4]), a4);
      a5 = fmaf(vv, bf2f((ushort)wv[5]), a5);
      a6 = fmaf(vv, bf2f((ushort)wv[6]), a6);
      a7 = fmaf(vv, bf2f((ushort)wv[7]), a7);
    }
    float* o = out + (size_t)row * d + base;
    *(float4*)o = make_float4(a0, a1, a2, a3);
    *(float4*)(o + 4) = make_float4(a4, a5, a6, a7);
  }
}

// fallback: gather directly from W_emb [d,m] fp32
__global__ __launch_bounds__(256)
void k_decode_g(const float* __restrict__ tvals, const int* __restrict__ tidx,
                const int* __restrict__ topk_d, const float* __restrict__ Wemb,
                float* __restrict__ out, int d, int m) {
  __shared__ float sv[KFIN];
  __shared__ int si[KFIN];
  const int row = blockIdx.x, tid = threadIdx.x;
  int kt = *topk_d;
  if (kt > KFIN) kt = KFIN;
  if (tid < kt) {
    sv[tid] = tvals[(size_t)row * KFIN + tid];
    si[tid] = tidx[(size_t)row * KFIN + tid];
  }
  __syncthreads();
  for (int base = tid * 8; base < d; base += 2048) {
    float acc[8] = {0, 0, 0, 0, 0, 0, 0, 0};
    for (int j = 0; j < kt; ++j) {
      float vv = sv[j];
      int ix = si[j];
#pragma unroll
      for (int e = 0; e < 8; ++e)
        acc[e] = fmaf(vv, Wemb[(size_t)(base + e) * m + ix], acc[e]);
    }
    float* o = out + (size_t)row * d + base;
    *(float4*)o = *(float4*)&acc[0];
    *(float4*)(o + 4) = *(float4*)&acc[4];
  }
}

// ---------------- host ----------------
extern "C" void kernel_launch(void* const* d_in, const int* in_sizes, int n_in,
                              void* d_out, int out_size, void* d_ws, size_t ws_size,
                              hipStream_t stream) {
  const float* act   = (const float*)d_in[0];
  const float* Wenc  = (const float*)d_in[1];
  const float* benc  = (const float*)d_in[2];
  const float* Wemb  = (const float*)d_in[3];
  const int*   steps = (const int*)d_in[4];
  const int*   topk  = (const int*)d_in[5];
  const int*   dwin  = (const int*)d_in[6];
  const int m = in_sizes[2];          // 16384
  const int d = in_sizes[1] / m;      // 2048
  const int rows = in_sizes[0] / d;   // 4096
  float* out = (float*)d_out;

  char* ws = (char*)d_ws;
  float* dead_sum = (float*)ws;
  int*   n_dead   = (int*)(ws + 8);
  int*   wl_count = (int*)(ws + 16);
  size_t off = 256;
  float* cvals = (float*)(ws + off); off += (size_t)rows * NC * 4;
  int*   cidx  = (int*)(ws + off);   off += (size_t)rows * NC * 4;
  float* tvals = (float*)(ws + off); off += (size_t)rows * KFIN * 4;
  int*   tidx  = (int*)(ws + off);   off += (size_t)rows * KFIN * 4;
  int*   rowflag = (int*)(ws + off); off += (size_t)rows * 4;
  int*   wl      = (int*)(ws + off); off += (size_t)rows * 4;
  double* dv     = (double*)(ws + off); off += (size_t)rows * NC * 8;
  ushort* Ast  = (ushort*)(ws + off); off += (size_t)rows * d * 4;  // hi+lo bf16
  ushort* Bst  = (ushort*)(ws + off); off += (size_t)m * d * 4;

  const size_t wembT_bytes = (size_t)m * d * sizeof(ushort);  // bf16
  const size_t row_bytes = (size_t)m * sizeof(float);
  size_t avail = (ws_size > off) ? ws_size - off : 0;

  ushort* WembT = nullptr;
  if (avail >= wembT_bytes + 256 * row_bytes) {
    WembT = (ushort*)(ws + off);
    off += wembT_bytes;
    avail -= wembT_bytes;
  }
  int chunk = (int)(avail / row_bytes);
  if (chunk > rows) chunk = rows;
  chunk &= ~255;                      // 256-row GEMM tiles
  if (chunk < 256) chunk = 256;
  float* preact = (float*)(ws + off);

  k_init<<<1, 1, 0, stream>>>(dead_sum, n_dead, wl_count);
  k_count_dead<<<(m + 255) / 256, 256, 0, stream>>>(steps, dwin, m, n_dead);

  int totA = rows * (d >> 5);
  int totB = m * (d >> 5);
  int nstage = (totA + totB + 255) / 256;
  int ntrans = WembT ? (m / 32) * (d / 32) : 0;
  k_prep<<<nstage + ntrans, 256, 0, stream>>>(act, Ast, totA, Wenc, Bst, totB, d,
                                              Wemb, WembT, d, m, nstage);

  for (int r0 = 0; r0 < rows; r0 += chunk) {
    int cr = rows - r0;
    if (cr > chunk) cr = chunk;
    int nbm = cr / 256;
    int nwg = nbm * (m / 256);
    k_gemm3<<<nwg, 512, 0, stream>>>(Ast, Bst, benc, preact, r0, d, m, nbm);
    k_topk<<<cr, 256, 0, stream>>>(preact, r0, steps, dwin, topk,
                                   cvals, cidx, dead_sum,
                                   rowflag, wl, wl_count, tvals, tidx);
  }

  k_dots<<<rows, 256, 0, stream>>>(wl, wl_count, cidx, act, Wenc, benc, dv, d);
  k_select<<<rows, 128, 0, stream>>>(cvals, cidx, rowflag, dv, topk, tvals, tidx);

  if (WembT) {
    k_decode_t<<<rows, 256, 0, stream>>>(tvals, tidx, topk, WembT, out, d);
  } else {
    k_decode_g<<<rows, 256, 0, stream>>>(tvals, tidx, topk, Wemb, out, d, m);
  }

  k_final<<<1, 1, 0, stream>>>(dead_sum, n_dead, out + (size_t)rows * d, (float)rows);
}

// Round 16
// 1099.029 us; speedup vs baseline: 1.3199x; 1.0469x over previous
//
#include <hip/hip_runtime.h>
#include <cfloat>
#include <climits>

// SparseEncoder forward, MI355X (gfx950). rows=4096, d=2048, m=16384, k=64.
// R16: fp16 2-pass encoder GEMM (A = hi+lo fp16 -> exact to 2^-22; B = single
// fp16). MFMA passes 3->2, B staging halved. pre_act err sigma ~2.8e-4 ->
// TAU raised to 2e-3 (flip = >5-sigma event). Schedule = R13's verified
// 4-phase double-buffer. Rest identical to R15.

typedef __attribute__((ext_vector_type(8))) short short8;
typedef __attribute__((ext_vector_type(4))) float f32x4;

#define NC      96
#define KFIN    64
#define TAU     2e-3f   // raised for fp16 2-pass (err sigma 2.8e-4; 5+ sigma margin)
#define AUXC    0.03125f
#define MCONC   16384
#define DDIM    2048
#define CAP     768

__device__ __forceinline__ ushort f2bf(float f) {
  unsigned u = __float_as_uint(f);
  u += 0x7fff + ((u >> 16) & 1);   // RTN-even
  return (ushort)(u >> 16);
}
__device__ __forceinline__ float bf2f(ushort h) {
  return __uint_as_float(((unsigned)h) << 16);
}
__device__ __forceinline__ ushort f2h(float f) {
  union { _Float16 h; ushort u; } cv;
  cv.h = (_Float16)f;              // RTN
  return cv.u;
}
__device__ __forceinline__ float h2f(ushort u) {
  union { _Float16 h; ushort u; } cv;
  cv.u = u;
  return (float)cv.h;
}

// ---------------- init / dead-concept bookkeeping ----------------
__global__ void k_init(float* dead_sum, int* n_dead, int* wl_count) {
  *dead_sum = 0.f;
  *n_dead = 0;
  *wl_count = 0;
}

__global__ void k_count_dead(const int* __restrict__ steps, const int* __restrict__ dw,
                             int m, int* __restrict__ n_dead) {
  int i = blockIdx.x * blockDim.x + threadIdx.x;
  if (i < m && steps[i] >= *dw) atomicAdd(n_dead, 1);
}

__global__ void k_final(const float* __restrict__ ds, const int* __restrict__ nd,
                        float* __restrict__ outp, float BT) {
  int n = *nd;
  float denom = fmaxf((float)n * BT, 1.0f);
  outp[0] = (n > 0) ? -((*ds) / denom) * AUXC : 0.0f;
}

// ---------------- fused prep: A hi/lo fp16, B single fp16, W_emb transpose->bf16 ----------------
__global__ __launch_bounds__(256)
void k_prep(const float* __restrict__ srcA, ushort* __restrict__ dstA, int totA,
            const float* __restrict__ srcB, ushort* __restrict__ dstB, int totB,
            int K,
            const float* __restrict__ Wemb, ushort* __restrict__ WembT,
            int d, int m, int nstage) {
  __shared__ float tile[32][33];
  const int b = blockIdx.x;
  if (b < nstage) {
    int idx = b * 256 + threadIdx.x;
    int nch = K >> 5;
    if (idx < totA) {
      // A: hi|lo fp16 per 32-chunk (64 ushorts/chunk, row stride 2K)
      int t = idx;
      int row = t / nch, c = t - row * nch;
      const float* s = srcA + (size_t)row * K + c * 32;
      float f[32];
#pragma unroll
      for (int qq = 0; qq < 8; ++qq) *(float4*)&f[qq * 4] = *(const float4*)(s + qq * 4);
      ushort hi[32];
#pragma unroll
      for (int e = 0; e < 32; ++e) hi[e] = f2h(f[e]);
      ushort* dd = dstA + (size_t)row * ((size_t)K * 2) + c * 64;
#pragma unroll
      for (int qq = 0; qq < 4; ++qq) {
        short8 o;
#pragma unroll
        for (int e = 0; e < 8; ++e) o[e] = (short)hi[qq * 8 + e];
        *(short8*)(dd + qq * 8) = o;
      }
#pragma unroll
      for (int qq = 0; qq < 4; ++qq) {
        short8 o;
#pragma unroll
        for (int e = 0; e < 8; ++e) {
          int ix = qq * 8 + e;
          o[e] = (short)f2h(f[ix] - h2f(hi[ix]));
        }
        *(short8*)(dd + 32 + qq * 8) = o;
      }
      return;
    }
    if (idx < totA + totB) {
      // B: single fp16 per element (32 ushorts/chunk, row stride K)
      int t = idx - totA;
      int row = t / nch, c = t - row * nch;
      const float* s = srcB + (size_t)row * K + c * 32;
      float f[32];
#pragma unroll
      for (int qq = 0; qq < 8; ++qq) *(float4*)&f[qq * 4] = *(const float4*)(s + qq * 4);
      ushort* dd = dstB + (size_t)row * (size_t)K + c * 32;
#pragma unroll
      for (int qq = 0; qq < 4; ++qq) {
        short8 o;
#pragma unroll
        for (int e = 0; e < 8; ++e) o[e] = (short)f2h(f[qq * 8 + e]);
        *(short8*)(dd + qq * 8) = o;
      }
      return;
    }
    return;
  }
  // transpose segment: W_emb [d,m] fp32 -> WembT [m,d] bf16
  const int tb = b - nstage;
  const int nmb = m >> 5;
  const int mb = (tb % nmb) * 32, db = (tb / nmb) * 32;
  const int tx = threadIdx.x & 31, ty = threadIdx.x >> 5;
#pragma unroll
  for (int i = 0; i < 32; i += 8)
    tile[ty + i][tx] = Wemb[(size_t)(db + ty + i) * m + mb + tx];
  __syncthreads();
#pragma unroll
  for (int i = 0; i < 32; i += 8)
    WembT[(size_t)(mb + ty + i) * d + db + tx] = f2bf(tile[tx][ty + i]);
}

// ---------------- fp16x2 MFMA GEMM, 256x256 tile, 8 waves, 4-phase pipeline ----------------
__device__ __forceinline__ void gload16(const void* g, void* l) {
  __builtin_amdgcn_global_load_lds((const __attribute__((address_space(1))) void*)g,
                                   (__attribute__((address_space(3))) void*)l, 16, 0, 0);
}

// 1-D grid, XCD-bijective swizzle (m204), bn fastest (A L2-resident per XCD).
// 512 threads = 8 waves (2x4). LDS: 2 x (A 32KB + B 16KB) = 96KB.
// A rows: 64 ushorts (hi|lo), slot swizzle s^(r&7). B rows: 32 ushorts (fp16),
// slot swizzle s^((r>>2)&3) -- both staged via pre-swizzled global source.
__global__ __launch_bounds__(512, 2)
void k_gemm3(const ushort* __restrict__ Ast, const ushort* __restrict__ Bst,
             const float* __restrict__ bias, float* __restrict__ C,
             int row0, int K, int m, int nbm) {
  __shared__ ushort As[2][256 * 64];
  __shared__ ushort Bs[2][256 * 32];
  const int tid = threadIdx.x;
  const int lane = tid & 63, w = tid >> 6;     // w in 0..7
  const int wm = w >> 2, wn = w & 3;           // 2 x 4 wave grid

  const int nbn = m >> 8;
  const int nwg = nbm * nbn;
  const int q = nwg >> 3, r = nwg & 7;
  const int x = blockIdx.x & 7, i0 = blockIdx.x >> 3;
  const int wg = (x < r) ? x * (q + 1) + i0 : r * (q + 1) + (x - r) * q + i0;
  const int bm = wg / nbn, bn = wg % nbn;      // bn fastest: A-panel L2 reuse

  const size_t K2 = (size_t)K * 2;             // A row stride (ushorts)
  const size_t KB = (size_t)K;                 // B row stride (ushorts)
  const int nch = K >> 5;

  // A staging: lane l of instr i -> LDS row 8i+(l>>3), phys slot l&7;
  // source logical slot = (l&7)^(l>>3)
  const int grA = lane >> 3;
  const int swzA = (((lane & 7) ^ grA) << 3);
  // B staging: lane l of instr i -> LDS row 16i+(l>>2), phys slot l&3;
  // source logical slot = (l&3)^((l>>4)&3)
  const int grB = lane >> 2;
  const int swzB = (((lane & 3) ^ ((lane >> 4) & 3)) << 3);

  const size_t arow0 = (size_t)(row0 + bm * 256);
  const size_t brow0 = (size_t)(bn * 256);

  f32x4 acc[8][4];
#pragma unroll
  for (int i = 0; i < 8; ++i)
#pragma unroll
    for (int j = 0; j < 4; ++j) acc[i][j] = (f32x4)(0.f);

  const int kg = lane >> 4;
  // A fragment read: row rbA=(lane&15)+16f; hi at phys slot kg^(rbA&7), lo at ^4
  const int shA = ((kg ^ (lane & 7)) << 3);
  const int rbaseA = (lane & 15) * 64;
  // B fragment read: row rbB=(lane&15)+16f; phys slot kg^((rbB>>2)&3)
  const int shB = ((kg ^ ((lane >> 2) & 3)) << 3);
  const int rbaseB = (lane & 15) * 32;

  auto STAGE_A = [&](int buf, int c) {
#pragma unroll
    for (int t = 0; t < 4; ++t) {
      int i = w * 4 + t;                 // 0..31 -> rows i*8+grA in 0..255
      int rr = i * 8 + grA;
      gload16(Ast + (arow0 + rr) * K2 + (size_t)c * 64 + swzA, (void*)(As[buf] + i * 512));
    }
  };
  auto STAGE_B = [&](int buf, int c) {
#pragma unroll
    for (int t = 0; t < 2; ++t) {
      int i = w * 2 + t;                 // 0..15 -> rows i*16+grB in 0..255
      int rr = i * 16 + grB;
      gload16(Bst + (brow0 + rr) * KB + (size_t)c * 32 + swzB, (void*)(Bs[buf] + i * 512));
    }
  };

  STAGE_A(0, 0);
  STAGE_B(0, 0);
  __syncthreads();                 // prologue drain: chunk 0 landed

  int cur = 0;
  for (int j = 0; j < nch; ++j) {
    short8 bh[4];
#pragma unroll
    for (int ph = 0; ph < 4; ++ph) {
      if (ph == 0) {
#pragma unroll
        for (int fn = 0; fn < 4; ++fn) {
          const ushort* pb = Bs[cur] + (wn * 64 + fn * 16) * 32 + rbaseB;
          bh[fn] = *(const short8*)(pb + shB);
        }
      }
      const ushort* pa0 = As[cur] + (wm * 128 + (2 * ph + 0) * 16) * 64 + rbaseA;
      const ushort* pa1 = As[cur] + (wm * 128 + (2 * ph + 1) * 16) * 64 + rbaseA;
      short8 ah0 = *(const short8*)(pa0 + shA);
      short8 al0 = *(const short8*)(pa0 + (shA ^ 32));
      short8 ah1 = *(const short8*)(pa1 + shA);
      short8 al1 = *(const short8*)(pa1 + (shA ^ 32));
      // stage next chunk: A-half at ph0, B-half at ph1.
      if (j + 1 < nch) {
        if (ph == 0) STAGE_A(cur ^ 1, j + 1);
        else if (ph == 1) STAGE_B(cur ^ 1, j + 1);
      }
      __builtin_amdgcn_s_barrier();
      __builtin_amdgcn_s_setprio(1);
#pragma unroll
      for (int fn = 0; fn < 4; ++fn) {
        acc[2 * ph + 0][fn] = __builtin_amdgcn_mfma_f32_16x16x32_f16(ah0, bh[fn], acc[2 * ph + 0][fn], 0, 0, 0);
        acc[2 * ph + 0][fn] = __builtin_amdgcn_mfma_f32_16x16x32_f16(al0, bh[fn], acc[2 * ph + 0][fn], 0, 0, 0);
        acc[2 * ph + 1][fn] = __builtin_amdgcn_mfma_f32_16x16x32_f16(ah1, bh[fn], acc[2 * ph + 1][fn], 0, 0, 0);
        acc[2 * ph + 1][fn] = __builtin_amdgcn_mfma_f32_16x16x32_f16(al1, bh[fn], acc[2 * ph + 1][fn], 0, 0, 0);
      }
      __builtin_amdgcn_s_setprio(0);
      __builtin_amdgcn_s_barrier();
    }
    __syncthreads();               // chunk-end: waits loads issued >=2 phases ago
    cur ^= 1;
  }

  // epilogue: C/D layout col=lane&15, row=(lane>>4)*4+reg (dtype-independent)
  const int orow = bm * 256 + wm * 128;
  const int ocol = bn * 256 + wn * 64;
#pragma unroll
  for (int fn = 0; fn < 4; ++fn) {
    float bb = bias[ocol + fn * 16 + (lane & 15)];
#pragma unroll
    for (int fm = 0; fm < 8; ++fm) {
      int rb = orow + fm * 16 + (lane >> 4) * 4;
#pragma unroll
      for (int rr = 0; rr < 4; ++rr)
        __builtin_nontemporal_store(acc[fm][fn][rr] + bb,
            &C[(size_t)(rb + rr) * m + ocol + fn * 16 + (lane & 15)]);
    }
  }
}

// ---------------- top-NC + fused flag/worklist + unflagged final write ----------------
__global__ __launch_bounds__(256)
void k_topk(const float* __restrict__ preact, int row0,
            const int* __restrict__ steps, const int* __restrict__ dw,
            const int* __restrict__ topk_d,
            float* __restrict__ cvals, int* __restrict__ cidx,
            float* __restrict__ dead_sum,
            int* __restrict__ rowflag, int* __restrict__ wl, int* __restrict__ wl_count,
            float* __restrict__ tvals, int* __restrict__ tidx) {
  __shared__ float dred[4];
  __shared__ float wmx[4], wmn[4];
  __shared__ float sm1[4], sm2[4];
  __shared__ int scnt;
  __shared__ int pos;
  __shared__ float cval_s[CAP];
  __shared__ int cidx_s[CAP];
  __shared__ float vk1_s, vk_s;
  __shared__ int flag_s;
  const int tid = threadIdx.x;
  const int lane = tid & 63;
  const int grow = row0 + blockIdx.x;
  const float* pr = preact + (size_t)blockIdx.x * MCONC;

  int kt = *topk_d;
  if (kt > KFIN) kt = KFIN;
  if (kt < 1) kt = 1;

  float v[64];
#pragma unroll
  for (int c = 0; c < 16; ++c) {
    const f32x4* p4 = (const f32x4*)(pr + (size_t)c * 1024 + tid * 4);
    f32x4 t4 = __builtin_nontemporal_load(p4);
    v[c * 4 + 0] = t4[0]; v[c * 4 + 1] = t4[1];
    v[c * 4 + 2] = t4[2]; v[c * 4 + 3] = t4[3];
  }

  // dead-concept masked sum (all-zero mask at init)
  int dwv = *dw;
  float ds = 0.f;
#pragma unroll
  for (int c = 0; c < 16; ++c) {
    int4 st = *(const int4*)(steps + c * 1024 + tid * 4);
    if (st.x >= dwv) ds += v[c * 4 + 0];
    if (st.y >= dwv) ds += v[c * 4 + 1];
    if (st.z >= dwv) ds += v[c * 4 + 2];
    if (st.w >= dwv) ds += v[c * 4 + 3];
  }
  for (int off = 32; off; off >>= 1) ds += __shfl_down(ds, off);
  if (lane == 0) dred[tid >> 6] = ds;

  // row max/min + mean/std moments (for the threshold probe)
  float mx = -FLT_MAX, mn = FLT_MAX, s1 = 0.f, s2 = 0.f;
#pragma unroll
  for (int i = 0; i < 64; ++i) {
    mx = fmaxf(mx, v[i]); mn = fminf(mn, v[i]);
    s1 += v[i]; s2 = fmaf(v[i], v[i], s2);
  }
  for (int off = 32; off; off >>= 1) {
    mx = fmaxf(mx, __shfl_xor(mx, off));
    mn = fminf(mn, __shfl_xor(mn, off));
    s1 += __shfl_xor(s1, off);
    s2 += __shfl_xor(s2, off);
  }
  if (lane == 0) { wmx[tid >> 6] = mx; wmn[tid >> 6] = mn; sm1[tid >> 6] = s1; sm2[tid >> 6] = s2; }
  __syncthreads();
  if (tid == 0) {
    float t = dred[0] + dred[1] + dred[2] + dred[3];
    if (t != 0.f) atomicAdd(dead_sum, t);
  }
  float row_mx = fmaxf(fmaxf(wmx[0], wmx[1]), fmaxf(wmx[2], wmx[3]));
  float row_mn = fminf(fminf(wmn[0], wmn[1]), fminf(wmn[2], wmn[3]));
  float T1 = sm1[0] + sm1[1] + sm1[2] + sm1[3];
  float T2 = sm2[0] + sm2[1] + sm2[2] + sm2[3];
  float mu = T1 * (1.f / 16384.f);
  float var = fmaxf(T2 * (1.f / 16384.f) - mu * mu, 0.f);
  float mid = mu + 2.0f * sqrtf(var);

  // threshold search: smart probe first, exact binary-search fallback
  float lo = row_mn - 1.0f, hi = row_mx;
  float t = lo;
  bool found = false;
  for (int it = 0; it < 23 && !found; ++it) {
    __syncthreads();
    if (tid == 0) scnt = 0;
    __syncthreads();
    int cl = 0;
#pragma unroll
    for (int i = 0; i < 64; ++i) cl += (v[i] > mid);
    for (int off = 32; off; off >>= 1) cl += __shfl_xor(cl, off);
    if (lane == 0) atomicAdd(&scnt, cl);
    __syncthreads();
    int cnt = scnt;
    if (cnt >= NC && cnt <= CAP) { t = mid; found = true; }
    else if (cnt < NC) hi = mid;
    else lo = mid;
    mid = 0.5f * (lo + hi);
  }
  if (!found) t = lo;  // count(>lo) >= NC invariant

  // compact candidates to LDS
  __syncthreads();
  if (tid == 0) pos = 0;
  __syncthreads();
#pragma unroll
  for (int i = 0; i < 64; ++i) {
    if (v[i] > t) {
      int p = atomicAdd(&pos, 1);
      if (p < CAP) {
        cval_s[p] = v[i];
        cidx_s[p] = ((i >> 2) << 10) | (tid << 2) | (i & 3);
      }
    }
  }
  __syncthreads();
  int Cn = pos < CAP ? pos : CAP;

  // parallel rank (strict total order: value desc, index asc).
  int rnk[3];
  float mvv[3];
  int mii[3];
#pragma unroll
  for (int jj = 0; jj < 3; ++jj) {
    int j = tid + jj * 256;
    rnk[jj] = INT_MAX;
    if (j < Cn) {
      float my = cval_s[j];
      int myidx = cidx_s[j];
      int rank = 0;
      for (int c = 0; c < Cn; ++c) {
        float o = cval_s[c];
        rank += (o > my) || (o == my && cidx_s[c] < myidx);
      }
      rnk[jj] = rank; mvv[jj] = my; mii[jj] = myidx;
      if (rank < NC) {
        cvals[(size_t)grow * NC + rank] = my;
        cidx[(size_t)grow * NC + rank] = myidx;
      }
      if (rank == kt - 1) vk1_s = my;
      if (rank == kt)     vk_s  = my;
    }
  }
  __syncthreads();
  if (tid == 0) {
    int f = (vk1_s - vk_s < TAU) ? 1 : 0;
    rowflag[grow] = f;
    flag_s = f;
    if (f) { int p = atomicAdd(wl_count, 1); wl[p] = grow; }
  }
  __syncthreads();
  if (!flag_s) {
#pragma unroll
    for (int jj = 0; jj < 3; ++jj) {
      if (rnk[jj] < kt) {
        tvals[(size_t)grow * KFIN + rnk[jj]] = mvv[jj];
        tidx[(size_t)grow * KFIN + rnk[jj]] = mii[jj];
      }
    }
  }
}

// ---------------- parallel fp64 candidate dots (worklist, grid-stride) ----------------
__global__ __launch_bounds__(256)
void k_dots(const int* __restrict__ wl, const int* __restrict__ wl_count,
            const int* __restrict__ cidx, const float* __restrict__ act,
            const float* __restrict__ Wenc, const float* __restrict__ bias,
            double* __restrict__ dv, int d) {
  __shared__ float arow[DDIM];
  const int total = (*wl_count) * 8;
  const int lane = threadIdx.x & 63, w = threadIdx.x >> 6;
  for (int b = blockIdx.x; b < total; b += gridDim.x) {
    const int row = wl[b >> 3], part = b & 7;
    __syncthreads();   // guard arow reuse across stride iterations
    for (int i = threadIdx.x; i < d; i += 256) arow[i] = act[(size_t)row * d + i];
    __syncthreads();
#pragma unroll
    for (int cc = 0; cc < 3; ++cc) {
      int c = part * 12 + w * 3 + cc;
      int ci = cidx[(size_t)row * NC + c];
      const float* wrow = Wenc + (size_t)ci * d;
      double s = 0.0;
      for (int i = lane; i < d; i += 64)
        s += (double)arow[i] * (double)wrow[i];
      for (int off = 32; off; off >>= 1) s += __shfl_down(s, off);
      if (lane == 0) dv[(size_t)row * NC + c] = s + (double)bias[ci];
    }
  }
}

// ---------------- final selection for FLAGGED rows only ----------------
__global__ __launch_bounds__(128)
void k_select(const float* __restrict__ cvals, const int* __restrict__ cidx,
              const int* __restrict__ rowflag, const double* __restrict__ dv,
              const int* __restrict__ topk_d,
              float* __restrict__ tvals, int* __restrict__ tidx) {
  const int row = blockIdx.x, tid = threadIdx.x;
  if (!rowflag[row]) return;   // unflagged rows already written by k_topk
  int kt = *topk_d;
  if (kt > KFIN) kt = KFIN;
  if (kt < 1) kt = 1;
  __shared__ double sdv[NC];
  if (tid < NC) sdv[tid] = dv[(size_t)row * NC + tid];
  __syncthreads();
  if (tid < NC) {
    double my = sdv[tid];
    int rank = 0;
#pragma unroll 8
    for (int c = 0; c < NC; ++c) {
      double v = sdv[c];
      rank += (v > my) || (v == my && c < tid);
    }
    if (rank < kt) {
      tvals[(size_t)row * KFIN + rank] = cvals[(size_t)row * NC + tid];
      tidx[(size_t)row * KFIN + rank] = cidx[(size_t)row * NC + tid];
    }
  }
}

// ---------------- sparse decode (bf16 transposed weights) ----------------
__global__ __launch_bounds__(256)
void k_decode_t(const float* __restrict__ tvals, const int* __restrict__ tidx,
                const int* __restrict__ topk_d, const ushort* __restrict__ Wt,
                float* __restrict__ out, int d) {
  __shared__ float sv[KFIN];
  __shared__ int si[KFIN];
  const int row = blockIdx.x, tid = threadIdx.x;
  int kt = *topk_d;
  if (kt > KFIN) kt = KFIN;
  if (tid < kt) {
    sv[tid] = tvals[(size_t)row * KFIN + tid];
    si[tid] = tidx[(size_t)row * KFIN + tid];
  }
  __syncthreads();
  for (int base = tid * 8; base < d; base += 2048) {
    float a0 = 0, a1 = 0, a2 = 0, a3 = 0, a4 = 0, a5 = 0, a6 = 0, a7 = 0;
#pragma unroll 4
    for (int j = 0; j < kt; ++j) {
      float vv = sv[j];
      short8 wv = *(const short8*)(Wt + (size_t)si[j] * d + base);
      a0 = fmaf(vv, bf2f((ushort)wv[0]), a0);
      a1 = fmaf(vv, bf2f((ushort)wv[1]), a1);
      a2 = fmaf(vv, bf2f((ushort)wv[2]), a2);
      a3 = fmaf(vv, bf2f((ushort)wv[3]), a3);
      a4 = fmaf(vv, bf2f((ushort)wv[4]), a4);
      a5 = fmaf(vv, bf2f((ushort)wv[5]), a5);
      a6 = fmaf(vv, bf2f((ushort)wv[6]), a6);
      a7 = fmaf(vv, bf2f((ushort)wv[7]), a7);
    }
    float* o = out + (size_t)row * d + base;
    *(float4*)o = make_float4(a0, a1, a2, a3);
    *(float4*)(o + 4) = make_float4(a4, a5, a6, a7);
  }
}

// fallback: gather directly from W_emb [d,m] fp32
__global__ __launch_bounds__(256)
void k_decode_g(const float* __restrict__ tvals, const int* __restrict__ tidx,
                const int* __restrict__ topk_d, const float* __restrict__ Wemb,
                float* __restrict__ out, int d, int m) {
  __shared__ float sv[KFIN];
  __shared__ int si[KFIN];
  const int row = blockIdx.x, tid = threadIdx.x;
  int kt = *topk_d;
  if (kt > KFIN) kt = KFIN;
  if (tid < kt) {
    sv[tid] = tvals[(size_t)row * KFIN + tid];
    si[tid] = tidx[(size_t)row * KFIN + tid];
  }
  __syncthreads();
  for (int base = tid * 8; base < d; base += 2048) {
    float acc[8] = {0, 0, 0, 0, 0, 0, 0, 0};
    for (int j = 0; j < kt; ++j) {
      float vv = sv[j];
      int ix = si[j];
#pragma unroll
      for (int e = 0; e < 8; ++e)
        acc[e] = fmaf(vv, Wemb[(size_t)(base + e) * m + ix], acc[e]);
    }
    float* o = out + (size_t)row * d + base;
    *(float4*)o = *(float4*)&acc[0];
    *(float4*)(o + 4) = *(float4*)&acc[4];
  }
}

// ---------------- host ----------------
extern "C" void kernel_launch(void* const* d_in, const int* in_sizes, int n_in,
                              void* d_out, int out_size, void* d_ws, size_t ws_size,
                              hipStream_t stream) {
  const float* act   = (const float*)d_in[0];
  const float* Wenc  = (const float*)d_in[1];
  const float* benc  = (const float*)d_in[2];
  const float* Wemb  = (const float*)d_in[3];
  const int*   steps = (const int*)d_in[4];
  const int*   topk  = (const int*)d_in[5];
  const int*   dwin  = (const int*)d_in[6];
  const int m = in_sizes[2];          // 16384
  const int d = in_sizes[1] / m;      // 2048
  const int rows = in_sizes[0] / d;   // 4096
  float* out = (float*)d_out;

  char* ws = (char*)d_ws;
  float* dead_sum = (float*)ws;
  int*   n_dead   = (int*)(ws + 8);
  int*   wl_count = (int*)(ws + 16);
  size_t off = 256;
  float* cvals = (float*)(ws + off); off += (size_t)rows * NC * 4;
  int*   cidx  = (int*)(ws + off);   off += (size_t)rows * NC * 4;
  float* tvals = (float*)(ws + off); off += (size_t)rows * KFIN * 4;
  int*   tidx  = (int*)(ws + off);   off += (size_t)rows * KFIN * 4;
  int*   rowflag = (int*)(ws + off); off += (size_t)rows * 4;
  int*   wl      = (int*)(ws + off); off += (size_t)rows * 4;
  double* dv     = (double*)(ws + off); off += (size_t)rows * NC * 8;
  ushort* Ast  = (ushort*)(ws + off); off += (size_t)rows * d * 4;  // hi+lo fp16
  ushort* Bst  = (ushort*)(ws + off); off += (size_t)m * d * 2;     // single fp16

  const size_t wembT_bytes = (size_t)m * d * sizeof(ushort);  // bf16
  const size_t row_bytes = (size_t)m * sizeof(float);
  size_t avail = (ws_size > off) ? ws_size - off : 0;

  ushort* WembT = nullptr;
  if (avail >= wembT_bytes + 256 * row_bytes) {
    WembT = (ushort*)(ws + off);
    off += wembT_bytes;
    avail -= wembT_bytes;
  }
  int chunk = (int)(avail / row_bytes);
  if (chunk > rows) chunk = rows;
  chunk &= ~255;                      // 256-row GEMM tiles
  if (chunk < 256) chunk = 256;
  float* preact = (float*)(ws + off);

  k_init<<<1, 1, 0, stream>>>(dead_sum, n_dead, wl_count);
  k_count_dead<<<(m + 255) / 256, 256, 0, stream>>>(steps, dwin, m, n_dead);

  int totA = rows * (d >> 5);
  int totB = m * (d >> 5);
  int nstage = (totA + totB + 255) / 256;
  int ntrans = WembT ? (m / 32) * (d / 32) : 0;
  k_prep<<<nstage + ntrans, 256, 0, stream>>>(act, Ast, totA, Wenc, Bst, totB, d,
                                              Wemb, WembT, d, m, nstage);

  for (int r0 = 0; r0 < rows; r0 += chunk) {
    int cr = rows - r0;
    if (cr > chunk) cr = chunk;
    int nbm = cr / 256;
    int nwg = nbm * (m / 256);
    k_gemm3<<<nwg, 512, 0, stream>>>(Ast, Bst, benc, preact, r0, d, m, nbm);
    k_topk<<<cr, 256, 0, stream>>>(preact, r0, steps, dwin, topk,
                                   cvals, cidx, dead_sum,
                                   rowflag, wl, wl_count, tvals, tidx);
  }

  k_dots<<<rows, 256, 0, stream>>>(wl, wl_count, cidx, act, Wenc, benc, dv, d);
  k_select<<<rows, 128, 0, stream>>>(cvals, cidx, rowflag, dv, topk, tvals, tidx);

  if (WembT) {
    k_decode_t<<<rows, 256, 0, stream>>>(tvals, tidx, topk, WembT, out, d);
  } else {
    k_decode_g<<<rows, 256, 0, stream>>>(tvals, tidx, topk, Wemb, out, d, m);
  }

  k_final<<<1, 1, 0, stream>>>(dead_sum, n_dead, out + (size_t)rows * d, (float)rows);
}

// Round 17
// 1097.127 us; speedup vs baseline: 1.3222x; 1.0017x over previous
//
#include <hip/hip_runtime.h>
#include <cfloat>
#include <climits>

// SparseEncoder forward, MI355X (gfx950). rows=4096, d=2048, m=16384, k=64.
// R17 = R16 + B LDS layout fix: paired-row 8-slot XOR swizzle (clone of the
// conflict-free A pattern; R16's 4-slot swizzle measured 8.4M bank conflicts).

typedef __attribute__((ext_vector_type(8))) short short8;
typedef __attribute__((ext_vector_type(4))) float f32x4;

#define NC      96
#define KFIN    64
#define TAU     2e-3f   // fp16 2-pass (err sigma 2.8e-4; 5+ sigma margin)
#define AUXC    0.03125f
#define MCONC   16384
#define DDIM    2048
#define CAP     768

__device__ __forceinline__ ushort f2bf(float f) {
  unsigned u = __float_as_uint(f);
  u += 0x7fff + ((u >> 16) & 1);   // RTN-even
  return (ushort)(u >> 16);
}
__device__ __forceinline__ float bf2f(ushort h) {
  return __uint_as_float(((unsigned)h) << 16);
}
__device__ __forceinline__ ushort f2h(float f) {
  union { _Float16 h; ushort u; } cv;
  cv.h = (_Float16)f;              // RTN
  return cv.u;
}
__device__ __forceinline__ float h2f(ushort u) {
  union { _Float16 h; ushort u; } cv;
  cv.u = u;
  return (float)cv.h;
}

// ---------------- init / dead-concept bookkeeping ----------------
__global__ void k_init(float* dead_sum, int* n_dead, int* wl_count) {
  *dead_sum = 0.f;
  *n_dead = 0;
  *wl_count = 0;
}

__global__ void k_count_dead(const int* __restrict__ steps, const int* __restrict__ dw,
                             int m, int* __restrict__ n_dead) {
  int i = blockIdx.x * blockDim.x + threadIdx.x;
  if (i < m && steps[i] >= *dw) atomicAdd(n_dead, 1);
}

__global__ void k_final(const float* __restrict__ ds, const int* __restrict__ nd,
                        float* __restrict__ outp, float BT) {
  int n = *nd;
  float denom = fmaxf((float)n * BT, 1.0f);
  outp[0] = (n > 0) ? -((*ds) / denom) * AUXC : 0.0f;
}

// ---------------- fused prep: A hi/lo fp16, B single fp16, W_emb transpose->bf16 ----------------
__global__ __launch_bounds__(256)
void k_prep(const float* __restrict__ srcA, ushort* __restrict__ dstA, int totA,
            const float* __restrict__ srcB, ushort* __restrict__ dstB, int totB,
            int K,
            const float* __restrict__ Wemb, ushort* __restrict__ WembT,
            int d, int m, int nstage) {
  __shared__ float tile[32][33];
  const int b = blockIdx.x;
  if (b < nstage) {
    int idx = b * 256 + threadIdx.x;
    int nch = K >> 5;
    if (idx < totA) {
      // A: hi|lo fp16 per 32-chunk (64 ushorts/chunk, row stride 2K)
      int t = idx;
      int row = t / nch, c = t - row * nch;
      const float* s = srcA + (size_t)row * K + c * 32;
      float f[32];
#pragma unroll
      for (int qq = 0; qq < 8; ++qq) *(float4*)&f[qq * 4] = *(const float4*)(s + qq * 4);
      ushort hi[32];
#pragma unroll
      for (int e = 0; e < 32; ++e) hi[e] = f2h(f[e]);
      ushort* dd = dstA + (size_t)row * ((size_t)K * 2) + c * 64;
#pragma unroll
      for (int qq = 0; qq < 4; ++qq) {
        short8 o;
#pragma unroll
        for (int e = 0; e < 8; ++e) o[e] = (short)hi[qq * 8 + e];
        *(short8*)(dd + qq * 8) = o;
      }
#pragma unroll
      for (int qq = 0; qq < 4; ++qq) {
        short8 o;
#pragma unroll
        for (int e = 0; e < 8; ++e) {
          int ix = qq * 8 + e;
          o[e] = (short)f2h(f[ix] - h2f(hi[ix]));
        }
        *(short8*)(dd + 32 + qq * 8) = o;
      }
      return;
    }
    if (idx < totA + totB) {
      // B: single fp16 per element (32 ushorts/chunk, row stride K)
      int t = idx - totA;
      int row = t / nch, c = t - row * nch;
      const float* s = srcB + (size_t)row * K + c * 32;
      float f[32];
#pragma unroll
      for (int qq = 0; qq < 8; ++qq) *(float4*)&f[qq * 4] = *(const float4*)(s + qq * 4);
      ushort* dd = dstB + (size_t)row * (size_t)K + c * 32;
#pragma unroll
      for (int qq = 0; qq < 4; ++qq) {
        short8 o;
#pragma unroll
        for (int e = 0; e < 8; ++e) o[e] = (short)f2h(f[qq * 8 + e]);
        *(short8*)(dd + qq * 8) = o;
      }
      return;
    }
    return;
  }
  // transpose segment: W_emb [d,m] fp32 -> WembT [m,d] bf16
  const int tb = b - nstage;
  const int nmb = m >> 5;
  const int mb = (tb % nmb) * 32, db = (tb / nmb) * 32;
  const int tx = threadIdx.x & 31, ty = threadIdx.x >> 5;
#pragma unroll
  for (int i = 0; i < 32; i += 8)
    tile[ty + i][tx] = Wemb[(size_t)(db + ty + i) * m + mb + tx];
  __syncthreads();
#pragma unroll
  for (int i = 0; i < 32; i += 8)
    WembT[(size_t)(mb + ty + i) * d + db + tx] = f2bf(tile[tx][ty + i]);
}

// ---------------- fp16x2 MFMA GEMM, 256x256 tile, 8 waves, 4-phase pipeline ----------------
__device__ __forceinline__ void gload16(const void* g, void* l) {
  __builtin_amdgcn_global_load_lds((const __attribute__((address_space(1))) void*)g,
                                   (__attribute__((address_space(3))) void*)l, 16, 0, 0);
}

// 1-D grid, XCD-bijective swizzle (m204), bn fastest (A L2-resident per XCD).
// 512 threads = 8 waves (2x4). LDS: 2 x (A 32KB + B 16KB) = 96KB.
// A LDS rows: 64 ushorts (hi|lo), slot swizzle s^(r&7).
// B LDS rows: 64 ushorts holding TWO B rows (2L: logical slots 0-3 = k-groups,
// 2L+1: slots 4-7), phys = logical ^ (L&7) -- identical bank structure to A
// (every phys slot hit exactly 2x per 16-lane group = free 2-way).
__global__ __launch_bounds__(512, 2)
void k_gemm3(const ushort* __restrict__ Ast, const ushort* __restrict__ Bst,
             const float* __restrict__ bias, float* __restrict__ C,
             int row0, int K, int m, int nbm) {
  __shared__ ushort As[2][256 * 64];
  __shared__ ushort Bs[2][128 * 64];
  const int tid = threadIdx.x;
  const int lane = tid & 63, w = tid >> 6;     // w in 0..7
  const int wm = w >> 2, wn = w & 3;           // 2 x 4 wave grid

  const int nbn = m >> 8;
  const int nwg = nbm * nbn;
  const int q = nwg >> 3, r = nwg & 7;
  const int x = blockIdx.x & 7, i0 = blockIdx.x >> 3;
  const int wg = (x < r) ? x * (q + 1) + i0 : r * (q + 1) + (x - r) * q + i0;
  const int bm = wg / nbn, bn = wg % nbn;      // bn fastest: A-panel L2 reuse

  const size_t K2 = (size_t)K * 2;             // A row stride (ushorts)
  const size_t KB = (size_t)K;                 // B row stride (ushorts)
  const int nch = K >> 5;

  // A staging: lane l of instr i -> LDS row 8i+(l>>3), phys slot l&7;
  // source logical slot = (l&7)^(l>>3)
  const int grA = lane >> 3;
  const int swzA = (((lane & 7) ^ grA) << 3);
  // B staging: lane l of instr i -> LDS row 8i+(l>>3), phys slot l&7;
  // logical = (l&7)^(l>>3); parity p = logical>>2, k-group kg = logical&3;
  // global B row = 16i + 2*(l>>3) + p; source k-offset = kg*8.
  const int lgB = (lane & 7) ^ grA;
  const int rowB = 2 * grA + (lgB >> 2);       // within instr's 16-row span
  const int koffB = (lgB & 3) * 8;

  const size_t arow0 = (size_t)(row0 + bm * 256);
  const size_t brow0 = (size_t)(bn * 256);

  f32x4 acc[8][4];
#pragma unroll
  for (int i = 0; i < 8; ++i)
#pragma unroll
    for (int j = 0; j < 4; ++j) acc[i][j] = (f32x4)(0.f);

  const int kg = lane >> 4;
  // A fragment read: row rbA=(lane&15)+16f; hi at phys slot kg^(rbA&7), lo at ^4
  const int shA = ((kg ^ (lane & 7)) << 3);
  const int rbaseA = (lane & 15) * 64;
  // B fragment read: B row rb = wn*64+fn*16+(lane&15); LDS row L = rb>>1 =
  // wn*32+fn*8+Lb with Lb=(lane&15)>>1; L&7 == Lb; parity = lane&1;
  // phys = (kg + (parity<<2)) ^ Lb  (lane-constant across fn).
  const int LbB = (lane & 15) >> 1;
  const int phB = ((kg + ((lane & 1) << 2)) ^ LbB) << 3;   // ushort offset
  const int rbaseB = LbB * 64;

  auto STAGE_A = [&](int buf, int c) {
#pragma unroll
    for (int t = 0; t < 4; ++t) {
      int i = w * 4 + t;                 // 0..31 -> rows i*8+grA in 0..255
      int rr = i * 8 + grA;
      gload16(Ast + (arow0 + rr) * K2 + (size_t)c * 64 + swzA, (void*)(As[buf] + i * 512));
    }
  };
  auto STAGE_B = [&](int buf, int c) {
#pragma unroll
    for (int t = 0; t < 2; ++t) {
      int i = w * 2 + t;                 // 0..15 -> B rows 16i..16i+15
      int rr = 16 * i + rowB;
      gload16(Bst + (brow0 + rr) * KB + (size_t)c * 32 + koffB, (void*)(Bs[buf] + i * 512));
    }
  };

  STAGE_A(0, 0);
  STAGE_B(0, 0);
  __syncthreads();                 // prologue drain: chunk 0 landed

  int cur = 0;
  for (int j = 0; j < nch; ++j) {
    short8 bh[4];
#pragma unroll
    for (int ph = 0; ph < 4; ++ph) {
      if (ph == 0) {
#pragma unroll
        for (int fn = 0; fn < 4; ++fn) {
          const ushort* pb = Bs[cur] + (wn * 32 + fn * 8) * 64 + rbaseB + phB;
          bh[fn] = *(const short8*)pb;
        }
      }
      const ushort* pa0 = As[cur] + (wm * 128 + (2 * ph + 0) * 16) * 64 + rbaseA;
      const ushort* pa1 = As[cur] + (wm * 128 + (2 * ph + 1) * 16) * 64 + rbaseA;
      short8 ah0 = *(const short8*)(pa0 + shA);
      short8 al0 = *(const short8*)(pa0 + (shA ^ 32));
      short8 ah1 = *(const short8*)(pa1 + shA);
      short8 al1 = *(const short8*)(pa1 + (shA ^ 32));
      // stage next chunk: A-half at ph0, B-half at ph1.
      if (j + 1 < nch) {
        if (ph == 0) STAGE_A(cur ^ 1, j + 1);
        else if (ph == 1) STAGE_B(cur ^ 1, j + 1);
      }
      __builtin_amdgcn_s_barrier();
      __builtin_amdgcn_s_setprio(1);
#pragma unroll
      for (int fn = 0; fn < 4; ++fn) {
        acc[2 * ph + 0][fn] = __builtin_amdgcn_mfma_f32_16x16x32_f16(ah0, bh[fn], acc[2 * ph + 0][fn], 0, 0, 0);
        acc[2 * ph + 0][fn] = __builtin_amdgcn_mfma_f32_16x16x32_f16(al0, bh[fn], acc[2 * ph + 0][fn], 0, 0, 0);
        acc[2 * ph + 1][fn] = __builtin_amdgcn_mfma_f32_16x16x32_f16(ah1, bh[fn], acc[2 * ph + 1][fn], 0, 0, 0);
        acc[2 * ph + 1][fn] = __builtin_amdgcn_mfma_f32_16x16x32_f16(al1, bh[fn], acc[2 * ph + 1][fn], 0, 0, 0);
      }
      __builtin_amdgcn_s_setprio(0);
      __builtin_amdgcn_s_barrier();
    }
    __syncthreads();               // chunk-end: waits loads issued >=2 phases ago
    cur ^= 1;
  }

  // epilogue: C/D layout col=lane&15, row=(lane>>4)*4+reg (dtype-independent)
  const int orow = bm * 256 + wm * 128;
  const int ocol = bn * 256 + wn * 64;
#pragma unroll
  for (int fn = 0; fn < 4; ++fn) {
    float bb = bias[ocol + fn * 16 + (lane & 15)];
#pragma unroll
    for (int fm = 0; fm < 8; ++fm) {
      int rb = orow + fm * 16 + (lane >> 4) * 4;
#pragma unroll
      for (int rr = 0; rr < 4; ++rr)
        __builtin_nontemporal_store(acc[fm][fn][rr] + bb,
            &C[(size_t)(rb + rr) * m + ocol + fn * 16 + (lane & 15)]);
    }
  }
}

// ---------------- top-NC + fused flag/worklist + unflagged final write ----------------
__global__ __launch_bounds__(256)
void k_topk(const float* __restrict__ preact, int row0,
            const int* __restrict__ steps, const int* __restrict__ dw,
            const int* __restrict__ topk_d,
            float* __restrict__ cvals, int* __restrict__ cidx,
            float* __restrict__ dead_sum,
            int* __restrict__ rowflag, int* __restrict__ wl, int* __restrict__ wl_count,
            float* __restrict__ tvals, int* __restrict__ tidx) {
  __shared__ float dred[4];
  __shared__ float wmx[4], wmn[4];
  __shared__ float sm1[4], sm2[4];
  __shared__ int scnt;
  __shared__ int pos;
  __shared__ float cval_s[CAP];
  __shared__ int cidx_s[CAP];
  __shared__ float vk1_s, vk_s;
  __shared__ int flag_s;
  const int tid = threadIdx.x;
  const int lane = tid & 63;
  const int grow = row0 + blockIdx.x;
  const float* pr = preact + (size_t)blockIdx.x * MCONC;

  int kt = *topk_d;
  if (kt > KFIN) kt = KFIN;
  if (kt < 1) kt = 1;

  float v[64];
#pragma unroll
  for (int c = 0; c < 16; ++c) {
    const f32x4* p4 = (const f32x4*)(pr + (size_t)c * 1024 + tid * 4);
    f32x4 t4 = __builtin_nontemporal_load(p4);
    v[c * 4 + 0] = t4[0]; v[c * 4 + 1] = t4[1];
    v[c * 4 + 2] = t4[2]; v[c * 4 + 3] = t4[3];
  }

  // dead-concept masked sum (all-zero mask at init)
  int dwv = *dw;
  float ds = 0.f;
#pragma unroll
  for (int c = 0; c < 16; ++c) {
    int4 st = *(const int4*)(steps + c * 1024 + tid * 4);
    if (st.x >= dwv) ds += v[c * 4 + 0];
    if (st.y >= dwv) ds += v[c * 4 + 1];
    if (st.z >= dwv) ds += v[c * 4 + 2];
    if (st.w >= dwv) ds += v[c * 4 + 3];
  }
  for (int off = 32; off; off >>= 1) ds += __shfl_down(ds, off);
  if (lane == 0) dred[tid >> 6] = ds;

  // row max/min + mean/std moments (for the threshold probe)
  float mx = -FLT_MAX, mn = FLT_MAX, s1 = 0.f, s2 = 0.f;
#pragma unroll
  for (int i = 0; i < 64; ++i) {
    mx = fmaxf(mx, v[i]); mn = fminf(mn, v[i]);
    s1 += v[i]; s2 = fmaf(v[i], v[i], s2);
  }
  for (int off = 32; off; off >>= 1) {
    mx = fmaxf(mx, __shfl_xor(mx, off));
    mn = fminf(mn, __shfl_xor(mn, off));
    s1 += __shfl_xor(s1, off);
    s2 += __shfl_xor(s2, off);
  }
  if (lane == 0) { wmx[tid >> 6] = mx; wmn[tid >> 6] = mn; sm1[tid >> 6] = s1; sm2[tid >> 6] = s2; }
  __syncthreads();
  if (tid == 0) {
    float t = dred[0] + dred[1] + dred[2] + dred[3];
    if (t != 0.f) atomicAdd(dead_sum, t);
  }
  float row_mx = fmaxf(fmaxf(wmx[0], wmx[1]), fmaxf(wmx[2], wmx[3]));
  float row_mn = fminf(fminf(wmn[0], wmn[1]), fminf(wmn[2], wmn[3]));
  float T1 = sm1[0] + sm1[1] + sm1[2] + sm1[3];
  float T2 = sm2[0] + sm2[1] + sm2[2] + sm2[3];
  float mu = T1 * (1.f / 16384.f);
  float var = fmaxf(T2 * (1.f / 16384.f) - mu * mu, 0.f);
  float mid = mu + 2.0f * sqrtf(var);

  // threshold search: smart probe first, exact binary-search fallback
  float lo = row_mn - 1.0f, hi = row_mx;
  float t = lo;
  bool found = false;
  for (int it = 0; it < 23 && !found; ++it) {
    __syncthreads();
    if (tid == 0) scnt = 0;
    __syncthreads();
    int cl = 0;
#pragma unroll
    for (int i = 0; i < 64; ++i) cl += (v[i] > mid);
    for (int off = 32; off; off >>= 1) cl += __shfl_xor(cl, off);
    if (lane == 0) atomicAdd(&scnt, cl);
    __syncthreads();
    int cnt = scnt;
    if (cnt >= NC && cnt <= CAP) { t = mid; found = true; }
    else if (cnt < NC) hi = mid;
    else lo = mid;
    mid = 0.5f * (lo + hi);
  }
  if (!found) t = lo;  // count(>lo) >= NC invariant

  // compact candidates to LDS
  __syncthreads();
  if (tid == 0) pos = 0;
  __syncthreads();
#pragma unroll
  for (int i = 0; i < 64; ++i) {
    if (v[i] > t) {
      int p = atomicAdd(&pos, 1);
      if (p < CAP) {
        cval_s[p] = v[i];
        cidx_s[p] = ((i >> 2) << 10) | (tid << 2) | (i & 3);
      }
    }
  }
  __syncthreads();
  int Cn = pos < CAP ? pos : CAP;

  // parallel rank (strict total order: value desc, index asc).
  int rnk[3];
  float mvv[3];
  int mii[3];
#pragma unroll
  for (int jj = 0; jj < 3; ++jj) {
    int j = tid + jj * 256;
    rnk[jj] = INT_MAX;
    if (j < Cn) {
      float my = cval_s[j];
      int myidx = cidx_s[j];
      int rank = 0;
      for (int c = 0; c < Cn; ++c) {
        float o = cval_s[c];
        rank += (o > my) || (o == my && cidx_s[c] < myidx);
      }
      rnk[jj] = rank; mvv[jj] = my; mii[jj] = myidx;
      if (rank < NC) {
        cvals[(size_t)grow * NC + rank] = my;
        cidx[(size_t)grow * NC + rank] = myidx;
      }
      if (rank == kt - 1) vk1_s = my;
      if (rank == kt)     vk_s  = my;
    }
  }
  __syncthreads();
  if (tid == 0) {
    int f = (vk1_s - vk_s < TAU) ? 1 : 0;
    rowflag[grow] = f;
    flag_s = f;
    if (f) { int p = atomicAdd(wl_count, 1); wl[p] = grow; }
  }
  __syncthreads();
  if (!flag_s) {
#pragma unroll
    for (int jj = 0; jj < 3; ++jj) {
      if (rnk[jj] < kt) {
        tvals[(size_t)grow * KFIN + rnk[jj]] = mvv[jj];
        tidx[(size_t)grow * KFIN + rnk[jj]] = mii[jj];
      }
    }
  }
}

// ---------------- parallel fp64 candidate dots (worklist, grid-stride) ----------------
__global__ __launch_bounds__(256)
void k_dots(const int* __restrict__ wl, const int* __restrict__ wl_count,
            const int* __restrict__ cidx, const float* __restrict__ act,
            const float* __restrict__ Wenc, const float* __restrict__ bias,
            double* __restrict__ dv, int d) {
  __shared__ float arow[DDIM];
  const int total = (*wl_count) * 8;
  const int lane = threadIdx.x & 63, w = threadIdx.x >> 6;
  for (int b = blockIdx.x; b < total; b += gridDim.x) {
    const int row = wl[b >> 3], part = b & 7;
    __syncthreads();   // guard arow reuse across stride iterations
    for (int i = threadIdx.x; i < d; i += 256) arow[i] = act[(size_t)row * d + i];
    __syncthreads();
#pragma unroll
    for (int cc = 0; cc < 3; ++cc) {
      int c = part * 12 + w * 3 + cc;
      int ci = cidx[(size_t)row * NC + c];
      const float* wrow = Wenc + (size_t)ci * d;
      double s = 0.0;
      for (int i = lane; i < d; i += 64)
        s += (double)arow[i] * (double)wrow[i];
      for (int off = 32; off; off >>= 1) s += __shfl_down(s, off);
      if (lane == 0) dv[(size_t)row * NC + c] = s + (double)bias[ci];
    }
  }
}

// ---------------- final selection for FLAGGED rows only ----------------
__global__ __launch_bounds__(128)
void k_select(const float* __restrict__ cvals, const int* __restrict__ cidx,
              const int* __restrict__ rowflag, const double* __restrict__ dv,
              const int* __restrict__ topk_d,
              float* __restrict__ tvals, int* __restrict__ tidx) {
  const int row = blockIdx.x, tid = threadIdx.x;
  if (!rowflag[row]) return;   // unflagged rows already written by k_topk
  int kt = *topk_d;
  if (kt > KFIN) kt = KFIN;
  if (kt < 1) kt = 1;
  __shared__ double sdv[NC];
  if (tid < NC) sdv[tid] = dv[(size_t)row * NC + tid];
  __syncthreads();
  if (tid < NC) {
    double my = sdv[tid];
    int rank = 0;
#pragma unroll 8
    for (int c = 0; c < NC; ++c) {
      double v = sdv[c];
      rank += (v > my) || (v == my && c < tid);
    }
    if (rank < kt) {
      tvals[(size_t)row * KFIN + rank] = cvals[(size_t)row * NC + tid];
      tidx[(size_t)row * KFIN + rank] = cidx[(size_t)row * NC + tid];
    }
  }
}

// ---------------- sparse decode (bf16 transposed weights) ----------------
__global__ __launch_bounds__(256)
void k_decode_t(const float* __restrict__ tvals, const int* __restrict__ tidx,
                const int* __restrict__ topk_d, const ushort* __restrict__ Wt,
                float* __restrict__ out, int d) {
  __shared__ float sv[KFIN];
  __shared__ int si[KFIN];
  const int row = blockIdx.x, tid = threadIdx.x;
  int kt = *topk_d;
  if (kt > KFIN) kt = KFIN;
  if (tid < kt) {
    sv[tid] = tvals[(size_t)row * KFIN + tid];
    si[tid] = tidx[(size_t)row * KFIN + tid];
  }
  __syncthreads();
  for (int base = tid * 8; base < d; base += 2048) {
    float a0 = 0, a1 = 0, a2 = 0, a3 = 0, a4 = 0, a5 = 0, a6 = 0, a7 = 0;
#pragma unroll 4
    for (int j = 0; j < kt; ++j) {
      float vv = sv[j];
      short8 wv = *(const short8*)(Wt + (size_t)si[j] * d + base);
      a0 = fmaf(vv, bf2f((ushort)wv[0]), a0);
      a1 = fmaf(vv, bf2f((ushort)wv[1]), a1);
      a2 = fmaf(vv, bf2f((ushort)wv[2]), a2);
      a3 = fmaf(vv, bf2f((ushort)wv[3]), a3);
      a4 = fmaf(vv, bf2f((ushort)wv[4]), a4);
      a5 = fmaf(vv, bf2f((ushort)wv[5]), a5);
      a6 = fmaf(vv, bf2f((ushort)wv[6]), a6);
      a7 = fmaf(vv, bf2f((ushort)wv[7]), a7);
    }
    float* o = out + (size_t)row * d + base;
    *(float4*)o = make_float4(a0, a1, a2, a3);
    *(float4*)(o + 4) = make_float4(a4, a5, a6, a7);
  }
}

// fallback: gather directly from W_emb [d,m] fp32
__global__ __launch_bounds__(256)
void k_decode_g(const float* __restrict__ tvals, const int* __restrict__ tidx,
                const int* __restrict__ topk_d, const float* __restrict__ Wemb,
                float* __restrict__ out, int d, int m) {
  __shared__ float sv[KFIN];
  __shared__ int si[KFIN];
  const int row = blockIdx.x, tid = threadIdx.x;
  int kt = *topk_d;
  if (kt > KFIN) kt = KFIN;
  if (tid < kt) {
    sv[tid] = tvals[(size_t)row * KFIN + tid];
    si[tid] = tidx[(size_t)row * KFIN + tid];
  }
  __syncthreads();
  for (int base = tid * 8; base < d; base += 2048) {
    float acc[8] = {0, 0, 0, 0, 0, 0, 0, 0};
    for (int j = 0; j < kt; ++j) {
      float vv = sv[j];
      int ix = si[j];
#pragma unroll
      for (int e = 0; e < 8; ++e)
        acc[e] = fmaf(vv, Wemb[(size_t)(base + e) * m + ix], acc[e]);
    }
    float* o = out + (size_t)row * d + base;
    *(float4*)o = *(float4*)&acc[0];
    *(float4*)(o + 4) = *(float4*)&acc[4];
  }
}

// ---------------- host ----------------
extern "C" void kernel_launch(void* const* d_in, const int* in_sizes, int n_in,
                              void* d_out, int out_size, void* d_ws, size_t ws_size,
                              hipStream_t stream) {
  const float* act   = (const float*)d_in[0];
  const float* Wenc  = (const float*)d_in[1];
  const float* benc  = (const float*)d_in[2];
  const float* Wemb  = (const float*)d_in[3];
  const int*   steps = (const int*)d_in[4];
  const int*   topk  = (const int*)d_in[5];
  const int*   dwin  = (const int*)d_in[6];
  const int m = in_sizes[2];          // 16384
  const int d = in_sizes[1] / m;      // 2048
  const int rows = in_sizes[0] / d;   // 4096
  float* out = (float*)d_out;

  char* ws = (char*)d_ws;
  float* dead_sum = (float*)ws;
  int*   n_dead   = (int*)(ws + 8);
  int*   wl_count = (int*)(ws + 16);
  size_t off = 256;
  float* cvals = (float*)(ws + off); off += (size_t)rows * NC * 4;
  int*   cidx  = (int*)(ws + off);   off += (size_t)rows * NC * 4;
  float* tvals = (float*)(ws + off); off += (size_t)rows * KFIN * 4;
  int*   tidx  = (int*)(ws + off);   off += (size_t)rows * KFIN * 4;
  int*   rowflag = (int*)(ws + off); off += (size_t)rows * 4;
  int*   wl      = (int*)(ws + off); off += (size_t)rows * 4;
  double* dv     = (double*)(ws + off); off += (size_t)rows * NC * 8;
  ushort* Ast  = (ushort*)(ws + off); off += (size_t)rows * d * 4;  // hi+lo fp16
  ushort* Bst  = (ushort*)(ws + off); off += (size_t)m * d * 2;     // single fp16

  const size_t wembT_bytes = (size_t)m * d * sizeof(ushort);  // bf16
  const size_t row_bytes = (size_t)m * sizeof(float);
  size_t avail = (ws_size > off) ? ws_size - off : 0;

  ushort* WembT = nullptr;
  if (avail >= wembT_bytes + 256 * row_bytes) {
    WembT = (ushort*)(ws + off);
    off += wembT_bytes;
    avail -= wembT_bytes;
  }
  int chunk = (int)(avail / row_bytes);
  if (chunk > rows) chunk = rows;
  chunk &= ~255;                      // 256-row GEMM tiles
  if (chunk < 256) chunk = 256;
  float* preact = (float*)(ws + off);

  k_init<<<1, 1, 0, stream>>>(dead_sum, n_dead, wl_count);
  k_count_dead<<<(m + 255) / 256, 256, 0, stream>>>(steps, dwin, m, n_dead);

  int totA = rows * (d >> 5);
  int totB = m * (d >> 5);
  int nstage = (totA + totB + 255) / 256;
  int ntrans = WembT ? (m / 32) * (d / 32) : 0;
  k_prep<<<nstage + ntrans, 256, 0, stream>>>(act, Ast, totA, Wenc, Bst, totB, d,
                                              Wemb, WembT, d, m, nstage);

  for (int r0 = 0; r0 < rows; r0 += chunk) {
    int cr = rows - r0;
    if (cr > chunk) cr = chunk;
    int nbm = cr / 256;
    int nwg = nbm * (m / 256);
    k_gemm3<<<nwg, 512, 0, stream>>>(Ast, Bst, benc, preact, r0, d, m, nbm);
    k_topk<<<cr, 256, 0, stream>>>(preact, r0, steps, dwin, topk,
                                   cvals, cidx, dead_sum,
                                   rowflag, wl, wl_count, tvals, tidx);
  }

  k_dots<<<rows, 256, 0, stream>>>(wl, wl_count, cidx, act, Wenc, benc, dv, d);
  k_select<<<rows, 128, 0, stream>>>(cvals, cidx, rowflag, dv, topk, tvals, tidx);

  if (WembT) {
    k_decode_t<<<rows, 256, 0, stream>>>(tvals, tidx, topk, WembT, out, d);
  } else {
    k_decode_g<<<rows, 256, 0, stream>>>(tvals, tidx, topk, Wemb, out, d, m);
  }

  k_final<<<1, 1, 0, stream>>>(dead_sum, n_dead, out + (size_t)rows * d, (float)rows);
}